// Round 5
// baseline (377.775 us; speedup 1.0000x reference)
//
#include <hip/hip_runtime.h>
#include <hip/hip_bf16.h>

// NeuralInelasticModel fused fwd + Jacobian, MFMA bf16, 16 samples/block.
// 65536 samples, NS=6, NI=8, H=256.
// out = [ydot(65536*6) | dy(65536*36) | de(65536*6) | dT(65536*6)]
// z2 (sign feeds m2 mask) via 3-term bf16 split (6 MFMA products) -> fp32-chain accuracy.
// V10 = V9 (R5 structure + XOR swizzle + cy hoist + phase-B unroll 2; 236us measured)
//  + launch_bounds(256,4): occupancy probe 3 -> 4 blocks/CU (12 -> 16 waves/CU).
//    Reg budget 170 -> 128; est. demand ~132 -> marginal spill ~16-32MB writes (~3us)
//    vs +33% TLP on a ~50%-stalled kernel. Single-variable change vs V9.

typedef unsigned short ushort_t;
typedef __attribute__((ext_vector_type(8))) short bf16x8;   // 8 bf16 = 4 VGPRs
typedef __attribute__((ext_vector_type(4))) float f32x4;

#define NSAMP (64 * 1024)
#define NG16 (NSAMP / 16)
#define OFF_YDOT 0
#define OFF_DY (NSAMP * 6)
#define OFF_DE (OFF_DY + NSAMP * 36)
#define OFF_DT (OFF_DE + NSAMP * 6)

// Weights repacked into MFMA B-fragment order:
// frag elem idx = ((nt*8 + kt)*64 + lane)*8 + jj,
// value = B[k = kt*32 + (lane>>4)*8 + jj][n = nt*16 + (lane&15)]
__device__ __align__(16) ushort_t g_w2T_hi[65536];   // z2 GEMM: B[k=j][n=h] = w2[h][j]
__device__ __align__(16) ushort_t g_w2T_mid[65536];
__device__ __align__(16) ushort_t g_w2T_lo[65536];
__device__ __align__(16) ushort_t g_w2B[65536];      // B GEMM:  B[k=h][n=j] = w2[h][j]
__device__ __align__(16) ushort_t g_w1e[4096];       // J GEMM:  B[k=j][n=kout] = w1[j][kout] (kout<8 else 0)
__device__ __align__(16) ushort_t g_w3b[1536];       // w3 bf16 row-major [6][256]

static __device__ __forceinline__ ushort_t f2bf(float f) {
    union { __hip_bfloat16 b; ushort_t u; } c;
    c.b = __float2bfloat16(f);
    return c.u;
}
static __device__ __forceinline__ float bf2f(ushort_t u) {
    union { ushort_t u; __hip_bfloat16 b; } c;
    c.u = u;
    return __bfloat162float(c.b);
}

// Bank swizzle for bf16 frag regions (region bases are 1KiB-aligned with zero bits[9:8]):
// fold addr bits [9:8] (quad/qd) into bank bits [6:5]. Involution; 16B-block-preserving.
static __device__ __forceinline__ int swzu(int E) { return E ^ ((E >> 3) & 0x30); }  // ushort idx
static __device__ __forceinline__ int swzo(int o) { return o ^ ((o >> 3) & 0x6); }   // 16B-octet idx

__global__ void prep_kernel(const float* __restrict__ w1, const float* __restrict__ w2,
                            const float* __restrict__ w3) {
    const int gtid = blockIdx.x * blockDim.x + threadIdx.x;
    const int stride = gridDim.x * blockDim.x;
    for (int idx = gtid; idx < 65536; idx += stride) {
        const int nt = idx >> 12, kt = (idx >> 9) & 7, L = (idx >> 3) & 63, jj = idx & 7;
        const int n = nt * 16 + (L & 15);
        const int k = kt * 32 + ((L >> 4) & 3) * 8 + jj;
        const float vT = w2[n * 256 + k];          // w2T: B[k=j][n=h]
        const ushort_t hi = f2bf(vT);
        const float r1 = vT - bf2f(hi);
        const ushort_t mid = f2bf(r1);
        g_w2T_hi[idx]  = hi;
        g_w2T_mid[idx] = mid;
        g_w2T_lo[idx]  = f2bf(r1 - bf2f(mid));
        g_w2B[idx] = f2bf(w2[k * 256 + n]);        // w2B: B[k=h][n=j]
    }
    for (int idx = gtid; idx < 4096; idx += stride) {
        const int kt = idx >> 9, L = (idx >> 3) & 63, jj = idx & 7;
        const int kout = L & 15;
        const int j = kt * 32 + ((L >> 4) & 3) * 8 + jj;
        g_w1e[idx] = (kout < 8) ? f2bf(w1[j * 8 + kout]) : (ushort_t)0;
    }
    for (int idx = gtid; idx < 1536; idx += stride) g_w3b[idx] = f2bf(w3[idx]);
}

// LDS layout (40960 B -> 4 blocks/CU), all bf16 frag regions XOR-swizzled:
//   [0, 8192)      v1hi A-frag [8 kt][64 lane][8 jj] bf16. Dead after phase B.
//                    Post-B alias: Jsh [48][8] f32 @0 (1536), ydsh[48] f32 @1536.
//   [8192, 32768)  v1mid @8192 (8192), v1lo @16384 (8192), xs @24576 (512).
//                    Post-B alias: A2/Bm A-frag [3 mt][8 kt][64][8] bf16 (24576).
//   [32768, 40960) v2B B-frag [8 kt][64][8] bf16; n-dim = sample 0..15; doubles as m2 mask.
#define SMEM_BYTES 40960

__global__ __launch_bounds__(256, 4) void fused_kernel(
    const float* __restrict__ y, const float* __restrict__ erate,
    const float* __restrict__ Tin, const float* __restrict__ w1,
    const float* __restrict__ b1, const float* __restrict__ b2,
    const float* __restrict__ b3, float* __restrict__ out)
{
    __shared__ __align__(16) char smem[SMEM_BYTES];
    ushort_t* v1hi  = (ushort_t*)(smem + 0);
    float*    Jsh   = (float*)(smem + 0);
    float*    ydsh  = (float*)(smem + 1536);
    ushort_t* v1mid = (ushort_t*)(smem + 8192);
    ushort_t* v1lo  = (ushort_t*)(smem + 16384);
    ushort_t* A2    = (ushort_t*)(smem + 8192);
    float*    xs    = (float*)(smem + 24576);
    ushort_t* v2B   = (ushort_t*)(smem + 32768);

    const int tid  = threadIdx.x;
    const int lane = tid & 63;
    const int wave = tid >> 6;
    const int l15  = lane & 15;
    const int quad = lane >> 4;

    // per-thread weight regs for z1 (thread tid == hidden unit j)
    float w1r[8];
#pragma unroll
    for (int k = 0; k < 8; ++k) w1r[k] = w1[tid * 8 + k];
    const float b1r = b1[tid];
    float b2v[4];
#pragma unroll
    for (int n = 0; n < 4; ++n) b2v[n] = b2[(wave * 4 + n) * 16 + l15];

    const int g = blockIdx.x;
    const int s0 = g * 16;

    // ---- stage x for 16 samples (vector loads -> LDS) ----
    if (tid < 128) {
        const int s = tid >> 3, k = tid & 7;
        float v;
        if (k < 6)       v = y[(s0 + s) * 6 + k];
        else if (k == 6) v = erate[s0 + s];
        else             v = Tin[s0 + s];
        xs[s * 8 + k] = v;
    }
    __syncthreads();

    // ---- z1 (exact fp32) + 3-way bf16 split of v1 (A-frag layout, swizzled) + reg m1 mask ----
    unsigned int m1self = 0;  // bit s = (z1[s][tid] > 0)
    {
        const int ktw = tid >> 5, qd = (tid >> 3) & 3, jj = tid & 7;
#pragma unroll 4
        for (int s = 0; s < 16; ++s) {
            float z = b1r;
#pragma unroll
            for (int k = 0; k < 8; ++k) z = fmaf(w1r[k], xs[s * 8 + k], z);
            const float v = fmaxf(z, 0.0f);
            m1self |= (v > 0.0f ? 1u : 0u) << s;
            const ushort_t hi = f2bf(v);
            const float r1 = v - bf2f(hi);
            const ushort_t mid = f2bf(r1);
            const int e = swzu((ktw * 64 + (s | (qd << 4))) * 8 + jj);
            v1hi[e]  = hi;
            v1mid[e] = mid;
            v1lo[e]  = f2bf(r1 - bf2f(mid));
        }
    }
    __syncthreads();  // (1) splits visible

    // ---- phase B: z2 = v1 @ w2^T, 3-way split (6 MFMAs), M=16(s) N=256(h) K=256(j) ----
    {
        f32x4 cz[4];
#pragma unroll
        for (int n = 0; n < 4; ++n) cz[n] = (f32x4){0, 0, 0, 0};
#pragma unroll 2
        for (int kt = 0; kt < 8; ++kt) {
            const int ao = swzo(kt * 64 + lane) * 8;
            bf16x8 ahi = *(const bf16x8*)&v1hi[ao];
            bf16x8 ami = *(const bf16x8*)&v1mid[ao];
            bf16x8 alo = *(const bf16x8*)&v1lo[ao];
#pragma unroll
            for (int n = 0; n < 4; ++n) {
                const int bidx = (((wave * 4 + n) * 8 + kt) * 64 + lane) * 8;
                bf16x8 bh = *(const bf16x8*)&g_w2T_hi[bidx];
                bf16x8 bm = *(const bf16x8*)&g_w2T_mid[bidx];
                bf16x8 bl = *(const bf16x8*)&g_w2T_lo[bidx];
                cz[n] = __builtin_amdgcn_mfma_f32_16x16x32_bf16(alo, bh, cz[n], 0, 0, 0);
                cz[n] = __builtin_amdgcn_mfma_f32_16x16x32_bf16(ami, bm, cz[n], 0, 0, 0);
                cz[n] = __builtin_amdgcn_mfma_f32_16x16x32_bf16(ahi, bl, cz[n], 0, 0, 0);
                cz[n] = __builtin_amdgcn_mfma_f32_16x16x32_bf16(ami, bh, cz[n], 0, 0, 0);
                cz[n] = __builtin_amdgcn_mfma_f32_16x16x32_bf16(ahi, bm, cz[n], 0, 0, 0);
                cz[n] = __builtin_amdgcn_mfma_f32_16x16x32_bf16(ahi, bh, cz[n], 0, 0, 0);
            }
        }
        // epilogue: v2 = relu(z2 + b2) -> v2B (B-frag layout, n=sample; doubles as m2)
#pragma unroll
        for (int n = 0; n < 4; ++n) {
            const int h = (wave * 4 + n) * 16 + l15;
            const int ktd = h >> 5, qd = (h >> 3) & 3, jj = h & 7;
#pragma unroll
            for (int r = 0; r < 4; ++r) {
                const int s = quad * 4 + r;  // C layout: row = quad*4 + reg
                const float v2 = fmaxf(cz[n][r] + b2v[n], 0.0f);
                v2B[swzu((ktd * 64 + (s | (qd << 4))) * 8 + jj)] = f2bf(v2);
            }
        }
    }
    __syncthreads();  // (2) v2B visible; also: all split reads done -> A2 region writable

    // ---- chunks of 8 samples: A2 build, ydot (wave 3), C (B=A2@w2), Bm, D (J=Bm@w1e), out ----
#pragma unroll 1
    for (int c = 0; c < 2; ++c) {
        // build A2[m = sl*6+i][h] = m2[sg][h] ? w3[i][h] : 0, A-frag layout (192 threads)
        if (tid < 192) {
            const int mt = tid >> 6;
            const int m = mt * 16 + l15;
            const int sl = m / 6, i = m - sl * 6;
            const int sg = c * 8 + sl;
#pragma unroll 2
            for (int kt = 0; kt < 8; ++kt) {
                bf16x8 vv = *(const bf16x8*)&v2B[swzo(kt * 64 + (sg | (quad << 4))) * 8];
                bf16x8 wv = *(const bf16x8*)&g_w3b[i * 256 + kt * 32 + quad * 8];
                bf16x8 o;
#pragma unroll
                for (int e = 0; e < 8; ++e)
                    o[e] = ((ushort_t)vv[e] != 0) ? wv[e] : (short)0;
                *(bf16x8*)&A2[swzo((mt * 8 + kt) * 64 + lane) * 8] = o;
            }
        }
        __syncthreads();  // (3) A2 visible

        // wave 3: ydot tile first (short loop; cy regs die before the cc loop).
        // ydsh writes here are ordered vs prev-chunk out-reads by barrier (3).
        if (wave == 3) {
            f32x4 cy[3];
#pragma unroll
            for (int mt = 0; mt < 3; ++mt) cy[mt] = (f32x4){0, 0, 0, 0};
#pragma unroll 2
            for (int kt = 0; kt < 8; ++kt) {
                bf16x8 bv = *(const bf16x8*)&v2B[swzo(kt * 64 + lane) * 8];
#pragma unroll
                for (int mt = 0; mt < 3; ++mt) {
                    bf16x8 a = *(const bf16x8*)&A2[swzo((mt * 8 + kt) * 64 + lane) * 8];
                    cy[mt] = __builtin_amdgcn_mfma_f32_16x16x32_bf16(a, bv, cy[mt], 0, 0, 0);
                }
            }
#pragma unroll
            for (int mt = 0; mt < 3; ++mt) {
#pragma unroll
                for (int r = 0; r < 4; ++r) {
                    const int m = mt * 16 + quad * 4 + r;
                    const int sl = m / 6, i = m - sl * 6;
                    if (l15 == c * 8 + sl) ydsh[m] = cy[mt][r] + b3[i];
                }
            }
        }

        // phase C: B = A2 @ w2 (M=48 N=256 K=256)
        f32x4 cc[3][4];
#pragma unroll
        for (int mt = 0; mt < 3; ++mt)
#pragma unroll
            for (int n = 0; n < 4; ++n) cc[mt][n] = (f32x4){0, 0, 0, 0};
#pragma unroll 2
        for (int kt = 0; kt < 8; ++kt) {
            bf16x8 a[3];
#pragma unroll
            for (int mt = 0; mt < 3; ++mt)
                a[mt] = *(const bf16x8*)&A2[swzo((mt * 8 + kt) * 64 + lane) * 8];
#pragma unroll
            for (int n = 0; n < 4; ++n) {
                bf16x8 b = *(const bf16x8*)&g_w2B[(((wave * 4 + n) * 8 + kt) * 64 + lane) * 8];
#pragma unroll
                for (int mt = 0; mt < 3; ++mt)
                    cc[mt][n] = __builtin_amdgcn_mfma_f32_16x16x32_bf16(a[mt], b, cc[mt][n], 0, 0, 0);
            }
        }
        __syncthreads();  // (4) all A2 reads complete before Bm overwrites

        // Bm = (B .* m1) -> bf16 back into A2 region (A-frag layout, swizzled).
        // m1 via in-wave shuffle: column j's mask is held by lane n*16+l15.
#pragma unroll
        for (int n = 0; n < 4; ++n) {
            const unsigned int mcol = (unsigned int)__shfl((int)m1self, n * 16 + l15, 64);
            const int j = (wave * 4 + n) * 16 + l15;  // C layout: col = lane&15
            const int ktd = j >> 5, qd = (j >> 3) & 3, jjd = j & 7;
#pragma unroll
            for (int mt = 0; mt < 3; ++mt) {
#pragma unroll
                for (int r = 0; r < 4; ++r) {
                    const int m = mt * 16 + quad * 4 + r;  // C layout: row = quad*4+reg
                    const int sg = c * 8 + m / 6;
                    const ushort_t bm =
                        ((mcol >> sg) & 1u) ? f2bf(cc[mt][n][r]) : (ushort_t)0;
                    A2[swzu(((mt * 8 + ktd) * 64 + ((m & 15) | (qd << 4))) * 8 + jjd)] = bm;
                }
            }
        }
        __syncthreads();  // (5) Bm visible (also orders prev-chunk out-reads vs Jsh writes)

        // phase D: J = Bm @ w1e (M=48 N=16 K=256); waves 0-2 (wave 3's ydot already done).
        if (wave < 3) {
            f32x4 dc = {0, 0, 0, 0};
#pragma unroll 2
            for (int kt = 0; kt < 8; ++kt) {
                bf16x8 a = *(const bf16x8*)&A2[swzo((wave * 8 + kt) * 64 + lane) * 8];
                bf16x8 b = *(const bf16x8*)&g_w1e[(kt * 64 + lane) * 8];
                dc = __builtin_amdgcn_mfma_f32_16x16x32_bf16(a, b, dc, 0, 0, 0);
            }
            if (l15 < 8) {
#pragma unroll
                for (int r = 0; r < 4; ++r) {
                    const int m = wave * 16 + quad * 4 + r;
                    Jsh[m * 8 + l15] = dc[r];
                }
            }
        }
        __syncthreads();  // (6) Jsh/ydsh visible (also: all Bm reads done -> next chunk may overwrite)

        // coalesced output for this chunk's 8 samples
        {
            const int s0c = s0 + c * 8;
            const long base6 = (long)s0c * 6;
            {
                const int u = tid;  // dy dwords 0..255
                const int s = u / 36, rem = u - s * 36, ii = rem / 6, jy = rem - ii * 6;
                out[OFF_DY + (long)s0c * 36 + u] = Jsh[(s * 6 + ii) * 8 + jy];
            }
            if (tid < 32) {  // dy dwords 256..287
                const int u = 256 + tid;
                const int s = u / 36, rem = u - s * 36, ii = rem / 6, jy = rem - ii * 6;
                out[OFF_DY + (long)s0c * 36 + u] = Jsh[(s * 6 + ii) * 8 + jy];
            }
            if (tid < 48) out[OFF_YDOT + base6 + tid] = ydsh[tid];
            const int t2 = tid - 64;
            if (t2 >= 0 && t2 < 48) out[OFF_DE + base6 + t2] = Jsh[t2 * 8 + 6];
            const int t3 = tid - 128;
            if (t3 >= 0 && t3 < 48) out[OFF_DT + base6 + t3] = Jsh[t3 * 8 + 7];
        }
    }
}

extern "C" void kernel_launch(void* const* d_in, const int* in_sizes, int n_in,
                              void* d_out, int out_size, void* d_ws, size_t ws_size,
                              hipStream_t stream) {
    // setup_inputs order: t(0,unused), y(1), erate(2), T(3), w1(4), w2(5), w3(6), b1(7), b2(8), b3(9)
    const float* y     = (const float*)d_in[1];
    const float* erate = (const float*)d_in[2];
    const float* Tin   = (const float*)d_in[3];
    const float* w1    = (const float*)d_in[4];
    const float* w2    = (const float*)d_in[5];
    const float* w3    = (const float*)d_in[6];
    const float* b1    = (const float*)d_in[7];
    const float* b2    = (const float*)d_in[8];
    const float* b3    = (const float*)d_in[9];
    float* out = (float*)d_out;

    prep_kernel<<<dim3(64), dim3(256), 0, stream>>>(w1, w2, w3);
    fused_kernel<<<dim3(NG16), dim3(256), 0, stream>>>(
        y, erate, Tin, w1, b1, b2, b3, out);
}

// Round 6
// 282.006 us; speedup vs baseline: 1.3396x; 1.3396x over previous
//
#include <hip/hip_runtime.h>
#include <hip/hip_bf16.h>

// NeuralInelasticModel fused fwd + Jacobian, MFMA bf16, 16 samples/block.
// 65536 samples, NS=6, NI=8, H=256.
// out = [ydot(65536*6) | dy(65536*36) | de(65536*6) | dT(65536*6)]
// z2 (sign feeds m2 mask) via 3-term bf16 split (6 MFMA products) -> fp32-chain accuracy.
// V11 = V9 exactly (R5 structure + XOR swizzle + cy hoist + phase-B unroll 2 +
//   launch_bounds(256,3); 236us measured, VGPR=84, spill-writes 48MB)
//  + T5: s_setprio(1) around the MFMA clusters (phases B, C, cy). Mechanism: 3 blocks/CU
//   staggered in phase -> SIMD hosts waves in different roles; prioritize the MFMA-
//   issuing wave over load/VALU-issuing waves. Single-variable A/B vs V9.
// R5 lesson (measured both sides): (256,4) reg-cap 128 < true demand ~148 -> 235MB spill,
// 315us. (256,3) is the occupancy/spill optimum. Do not raise occupancy again.

typedef unsigned short ushort_t;
typedef __attribute__((ext_vector_type(8))) short bf16x8;   // 8 bf16 = 4 VGPRs
typedef __attribute__((ext_vector_type(4))) float f32x4;

#define NSAMP (64 * 1024)
#define NG16 (NSAMP / 16)
#define OFF_YDOT 0
#define OFF_DY (NSAMP * 6)
#define OFF_DE (OFF_DY + NSAMP * 36)
#define OFF_DT (OFF_DE + NSAMP * 6)

// Weights repacked into MFMA B-fragment order:
// frag elem idx = ((nt*8 + kt)*64 + lane)*8 + jj,
// value = B[k = kt*32 + (lane>>4)*8 + jj][n = nt*16 + (lane&15)]
__device__ __align__(16) ushort_t g_w2T_hi[65536];   // z2 GEMM: B[k=j][n=h] = w2[h][j]
__device__ __align__(16) ushort_t g_w2T_mid[65536];
__device__ __align__(16) ushort_t g_w2T_lo[65536];
__device__ __align__(16) ushort_t g_w2B[65536];      // B GEMM:  B[k=h][n=j] = w2[h][j]
__device__ __align__(16) ushort_t g_w1e[4096];       // J GEMM:  B[k=j][n=kout] = w1[j][kout] (kout<8 else 0)
__device__ __align__(16) ushort_t g_w3b[1536];       // w3 bf16 row-major [6][256]

static __device__ __forceinline__ ushort_t f2bf(float f) {
    union { __hip_bfloat16 b; ushort_t u; } c;
    c.b = __float2bfloat16(f);
    return c.u;
}
static __device__ __forceinline__ float bf2f(ushort_t u) {
    union { ushort_t u; __hip_bfloat16 b; } c;
    c.u = u;
    return __bfloat162float(c.b);
}

// Bank swizzle for bf16 frag regions (region bases are 1KiB-aligned with zero bits[9:8]):
// fold addr bits [9:8] (quad/qd) into bank bits [6:5]. Involution; 16B-block-preserving.
static __device__ __forceinline__ int swzu(int E) { return E ^ ((E >> 3) & 0x30); }  // ushort idx
static __device__ __forceinline__ int swzo(int o) { return o ^ ((o >> 3) & 0x6); }   // 16B-octet idx

__global__ void prep_kernel(const float* __restrict__ w1, const float* __restrict__ w2,
                            const float* __restrict__ w3) {
    const int gtid = blockIdx.x * blockDim.x + threadIdx.x;
    const int stride = gridDim.x * blockDim.x;
    for (int idx = gtid; idx < 65536; idx += stride) {
        const int nt = idx >> 12, kt = (idx >> 9) & 7, L = (idx >> 3) & 63, jj = idx & 7;
        const int n = nt * 16 + (L & 15);
        const int k = kt * 32 + ((L >> 4) & 3) * 8 + jj;
        const float vT = w2[n * 256 + k];          // w2T: B[k=j][n=h]
        const ushort_t hi = f2bf(vT);
        const float r1 = vT - bf2f(hi);
        const ushort_t mid = f2bf(r1);
        g_w2T_hi[idx]  = hi;
        g_w2T_mid[idx] = mid;
        g_w2T_lo[idx]  = f2bf(r1 - bf2f(mid));
        g_w2B[idx] = f2bf(w2[k * 256 + n]);        // w2B: B[k=h][n=j]
    }
    for (int idx = gtid; idx < 4096; idx += stride) {
        const int kt = idx >> 9, L = (idx >> 3) & 63, jj = idx & 7;
        const int kout = L & 15;
        const int j = kt * 32 + ((L >> 4) & 3) * 8 + jj;
        g_w1e[idx] = (kout < 8) ? f2bf(w1[j * 8 + kout]) : (ushort_t)0;
    }
    for (int idx = gtid; idx < 1536; idx += stride) g_w3b[idx] = f2bf(w3[idx]);
}

// LDS layout (40960 B), all bf16 frag regions XOR-swizzled:
//   [0, 8192)      v1hi A-frag [8 kt][64 lane][8 jj] bf16. Dead after phase B.
//                    Post-B alias: Jsh [48][8] f32 @0 (1536), ydsh[48] f32 @1536.
//   [8192, 32768)  v1mid @8192 (8192), v1lo @16384 (8192), xs @24576 (512).
//                    Post-B alias: A2/Bm A-frag [3 mt][8 kt][64][8] bf16 (24576).
//   [32768, 40960) v2B B-frag [8 kt][64][8] bf16; n-dim = sample 0..15; doubles as m2 mask.
#define SMEM_BYTES 40960

__global__ __launch_bounds__(256, 3) void fused_kernel(
    const float* __restrict__ y, const float* __restrict__ erate,
    const float* __restrict__ Tin, const float* __restrict__ w1,
    const float* __restrict__ b1, const float* __restrict__ b2,
    const float* __restrict__ b3, float* __restrict__ out)
{
    __shared__ __align__(16) char smem[SMEM_BYTES];
    ushort_t* v1hi  = (ushort_t*)(smem + 0);
    float*    Jsh   = (float*)(smem + 0);
    float*    ydsh  = (float*)(smem + 1536);
    ushort_t* v1mid = (ushort_t*)(smem + 8192);
    ushort_t* v1lo  = (ushort_t*)(smem + 16384);
    ushort_t* A2    = (ushort_t*)(smem + 8192);
    float*    xs    = (float*)(smem + 24576);
    ushort_t* v2B   = (ushort_t*)(smem + 32768);

    const int tid  = threadIdx.x;
    const int lane = tid & 63;
    const int wave = tid >> 6;
    const int l15  = lane & 15;
    const int quad = lane >> 4;

    // per-thread weight regs for z1 (thread tid == hidden unit j)
    float w1r[8];
#pragma unroll
    for (int k = 0; k < 8; ++k) w1r[k] = w1[tid * 8 + k];
    const float b1r = b1[tid];
    float b2v[4];
#pragma unroll
    for (int n = 0; n < 4; ++n) b2v[n] = b2[(wave * 4 + n) * 16 + l15];

    const int g = blockIdx.x;
    const int s0 = g * 16;

    // ---- stage x for 16 samples (vector loads -> LDS) ----
    if (tid < 128) {
        const int s = tid >> 3, k = tid & 7;
        float v;
        if (k < 6)       v = y[(s0 + s) * 6 + k];
        else if (k == 6) v = erate[s0 + s];
        else             v = Tin[s0 + s];
        xs[s * 8 + k] = v;
    }
    __syncthreads();

    // ---- z1 (exact fp32) + 3-way bf16 split of v1 (A-frag layout, swizzled) + reg m1 mask ----
    unsigned int m1self = 0;  // bit s = (z1[s][tid] > 0)
    {
        const int ktw = tid >> 5, qd = (tid >> 3) & 3, jj = tid & 7;
#pragma unroll 4
        for (int s = 0; s < 16; ++s) {
            float z = b1r;
#pragma unroll
            for (int k = 0; k < 8; ++k) z = fmaf(w1r[k], xs[s * 8 + k], z);
            const float v = fmaxf(z, 0.0f);
            m1self |= (v > 0.0f ? 1u : 0u) << s;
            const ushort_t hi = f2bf(v);
            const float r1 = v - bf2f(hi);
            const ushort_t mid = f2bf(r1);
            const int e = swzu((ktw * 64 + (s | (qd << 4))) * 8 + jj);
            v1hi[e]  = hi;
            v1mid[e] = mid;
            v1lo[e]  = f2bf(r1 - bf2f(mid));
        }
    }
    __syncthreads();  // (1) splits visible

    // ---- phase B: z2 = v1 @ w2^T, 3-way split (6 MFMAs), M=16(s) N=256(h) K=256(j) ----
    {
        f32x4 cz[4];
#pragma unroll
        for (int n = 0; n < 4; ++n) cz[n] = (f32x4){0, 0, 0, 0};
#pragma unroll 2
        for (int kt = 0; kt < 8; ++kt) {
            const int ao = swzo(kt * 64 + lane) * 8;
            bf16x8 ahi = *(const bf16x8*)&v1hi[ao];
            bf16x8 ami = *(const bf16x8*)&v1mid[ao];
            bf16x8 alo = *(const bf16x8*)&v1lo[ao];
#pragma unroll
            for (int n = 0; n < 4; ++n) {
                const int bidx = (((wave * 4 + n) * 8 + kt) * 64 + lane) * 8;
                bf16x8 bh = *(const bf16x8*)&g_w2T_hi[bidx];
                bf16x8 bm = *(const bf16x8*)&g_w2T_mid[bidx];
                bf16x8 bl = *(const bf16x8*)&g_w2T_lo[bidx];
                __builtin_amdgcn_s_setprio(1);
                cz[n] = __builtin_amdgcn_mfma_f32_16x16x32_bf16(alo, bh, cz[n], 0, 0, 0);
                cz[n] = __builtin_amdgcn_mfma_f32_16x16x32_bf16(ami, bm, cz[n], 0, 0, 0);
                cz[n] = __builtin_amdgcn_mfma_f32_16x16x32_bf16(ahi, bl, cz[n], 0, 0, 0);
                cz[n] = __builtin_amdgcn_mfma_f32_16x16x32_bf16(ami, bh, cz[n], 0, 0, 0);
                cz[n] = __builtin_amdgcn_mfma_f32_16x16x32_bf16(ahi, bm, cz[n], 0, 0, 0);
                cz[n] = __builtin_amdgcn_mfma_f32_16x16x32_bf16(ahi, bh, cz[n], 0, 0, 0);
                __builtin_amdgcn_s_setprio(0);
            }
        }
        // epilogue: v2 = relu(z2 + b2) -> v2B (B-frag layout, n=sample; doubles as m2)
#pragma unroll
        for (int n = 0; n < 4; ++n) {
            const int h = (wave * 4 + n) * 16 + l15;
            const int ktd = h >> 5, qd = (h >> 3) & 3, jj = h & 7;
#pragma unroll
            for (int r = 0; r < 4; ++r) {
                const int s = quad * 4 + r;  // C layout: row = quad*4 + reg
                const float v2 = fmaxf(cz[n][r] + b2v[n], 0.0f);
                v2B[swzu((ktd * 64 + (s | (qd << 4))) * 8 + jj)] = f2bf(v2);
            }
        }
    }
    __syncthreads();  // (2) v2B visible; also: all split reads done -> A2 region writable

    // ---- chunks of 8 samples: A2 build, ydot (wave 3), C (B=A2@w2), Bm, D (J=Bm@w1e), out ----
#pragma unroll 1
    for (int c = 0; c < 2; ++c) {
        // build A2[m = sl*6+i][h] = m2[sg][h] ? w3[i][h] : 0, A-frag layout (192 threads)
        if (tid < 192) {
            const int mt = tid >> 6;
            const int m = mt * 16 + l15;
            const int sl = m / 6, i = m - sl * 6;
            const int sg = c * 8 + sl;
#pragma unroll 2
            for (int kt = 0; kt < 8; ++kt) {
                bf16x8 vv = *(const bf16x8*)&v2B[swzo(kt * 64 + (sg | (quad << 4))) * 8];
                bf16x8 wv = *(const bf16x8*)&g_w3b[i * 256 + kt * 32 + quad * 8];
                bf16x8 o;
#pragma unroll
                for (int e = 0; e < 8; ++e)
                    o[e] = ((ushort_t)vv[e] != 0) ? wv[e] : (short)0;
                *(bf16x8*)&A2[swzo((mt * 8 + kt) * 64 + lane) * 8] = o;
            }
        }
        __syncthreads();  // (3) A2 visible

        // wave 3: ydot tile first (short loop; cy regs die before the cc loop).
        // ydsh writes here are ordered vs prev-chunk out-reads by barrier (3).
        if (wave == 3) {
            f32x4 cy[3];
#pragma unroll
            for (int mt = 0; mt < 3; ++mt) cy[mt] = (f32x4){0, 0, 0, 0};
#pragma unroll 2
            for (int kt = 0; kt < 8; ++kt) {
                bf16x8 bv = *(const bf16x8*)&v2B[swzo(kt * 64 + lane) * 8];
                __builtin_amdgcn_s_setprio(1);
#pragma unroll
                for (int mt = 0; mt < 3; ++mt) {
                    bf16x8 a = *(const bf16x8*)&A2[swzo((mt * 8 + kt) * 64 + lane) * 8];
                    cy[mt] = __builtin_amdgcn_mfma_f32_16x16x32_bf16(a, bv, cy[mt], 0, 0, 0);
                }
                __builtin_amdgcn_s_setprio(0);
            }
#pragma unroll
            for (int mt = 0; mt < 3; ++mt) {
#pragma unroll
                for (int r = 0; r < 4; ++r) {
                    const int m = mt * 16 + quad * 4 + r;
                    const int sl = m / 6, i = m - sl * 6;
                    if (l15 == c * 8 + sl) ydsh[m] = cy[mt][r] + b3[i];
                }
            }
        }

        // phase C: B = A2 @ w2 (M=48 N=256 K=256)
        f32x4 cc[3][4];
#pragma unroll
        for (int mt = 0; mt < 3; ++mt)
#pragma unroll
            for (int n = 0; n < 4; ++n) cc[mt][n] = (f32x4){0, 0, 0, 0};
#pragma unroll 2
        for (int kt = 0; kt < 8; ++kt) {
            bf16x8 a[3];
#pragma unroll
            for (int mt = 0; mt < 3; ++mt)
                a[mt] = *(const bf16x8*)&A2[swzo((mt * 8 + kt) * 64 + lane) * 8];
#pragma unroll
            for (int n = 0; n < 4; ++n) {
                bf16x8 b = *(const bf16x8*)&g_w2B[(((wave * 4 + n) * 8 + kt) * 64 + lane) * 8];
                __builtin_amdgcn_s_setprio(1);
#pragma unroll
                for (int mt = 0; mt < 3; ++mt)
                    cc[mt][n] = __builtin_amdgcn_mfma_f32_16x16x32_bf16(a[mt], b, cc[mt][n], 0, 0, 0);
                __builtin_amdgcn_s_setprio(0);
            }
        }
        __syncthreads();  // (4) all A2 reads complete before Bm overwrites

        // Bm = (B .* m1) -> bf16 back into A2 region (A-frag layout, swizzled).
        // m1 via in-wave shuffle: column j's mask is held by lane n*16+l15.
#pragma unroll
        for (int n = 0; n < 4; ++n) {
            const unsigned int mcol = (unsigned int)__shfl((int)m1self, n * 16 + l15, 64);
            const int j = (wave * 4 + n) * 16 + l15;  // C layout: col = lane&15
            const int ktd = j >> 5, qd = (j >> 3) & 3, jjd = j & 7;
#pragma unroll
            for (int mt = 0; mt < 3; ++mt) {
#pragma unroll
                for (int r = 0; r < 4; ++r) {
                    const int m = mt * 16 + quad * 4 + r;  // C layout: row = quad*4+reg
                    const int sg = c * 8 + m / 6;
                    const ushort_t bm =
                        ((mcol >> sg) & 1u) ? f2bf(cc[mt][n][r]) : (ushort_t)0;
                    A2[swzu(((mt * 8 + ktd) * 64 + ((m & 15) | (qd << 4))) * 8 + jjd)] = bm;
                }
            }
        }
        __syncthreads();  // (5) Bm visible (also orders prev-chunk out-reads vs Jsh writes)

        // phase D: J = Bm @ w1e (M=48 N=16 K=256); waves 0-2 (wave 3's ydot already done).
        if (wave < 3) {
            f32x4 dc = {0, 0, 0, 0};
#pragma unroll 2
            for (int kt = 0; kt < 8; ++kt) {
                bf16x8 a = *(const bf16x8*)&A2[swzo((wave * 8 + kt) * 64 + lane) * 8];
                bf16x8 b = *(const bf16x8*)&g_w1e[(kt * 64 + lane) * 8];
                dc = __builtin_amdgcn_mfma_f32_16x16x32_bf16(a, b, dc, 0, 0, 0);
            }
            if (l15 < 8) {
#pragma unroll
                for (int r = 0; r < 4; ++r) {
                    const int m = wave * 16 + quad * 4 + r;
                    Jsh[m * 8 + l15] = dc[r];
                }
            }
        }
        __syncthreads();  // (6) Jsh/ydsh visible (also: all Bm reads done -> next chunk may overwrite)

        // coalesced output for this chunk's 8 samples
        {
            const int s0c = s0 + c * 8;
            const long base6 = (long)s0c * 6;
            {
                const int u = tid;  // dy dwords 0..255
                const int s = u / 36, rem = u - s * 36, ii = rem / 6, jy = rem - ii * 6;
                out[OFF_DY + (long)s0c * 36 + u] = Jsh[(s * 6 + ii) * 8 + jy];
            }
            if (tid < 32) {  // dy dwords 256..287
                const int u = 256 + tid;
                const int s = u / 36, rem = u - s * 36, ii = rem / 6, jy = rem - ii * 6;
                out[OFF_DY + (long)s0c * 36 + u] = Jsh[(s * 6 + ii) * 8 + jy];
            }
            if (tid < 48) out[OFF_YDOT + base6 + tid] = ydsh[tid];
            const int t2 = tid - 64;
            if (t2 >= 0 && t2 < 48) out[OFF_DE + base6 + t2] = Jsh[t2 * 8 + 6];
            const int t3 = tid - 128;
            if (t3 >= 0 && t3 < 48) out[OFF_DT + base6 + t3] = Jsh[t3 * 8 + 7];
        }
    }
}

extern "C" void kernel_launch(void* const* d_in, const int* in_sizes, int n_in,
                              void* d_out, int out_size, void* d_ws, size_t ws_size,
                              hipStream_t stream) {
    // setup_inputs order: t(0,unused), y(1), erate(2), T(3), w1(4), w2(5), w3(6), b1(7), b2(8), b3(9)
    const float* y     = (const float*)d_in[1];
    const float* erate = (const float*)d_in[2];
    const float* Tin   = (const float*)d_in[3];
    const float* w1    = (const float*)d_in[4];
    const float* w2    = (const float*)d_in[5];
    const float* w3    = (const float*)d_in[6];
    const float* b1    = (const float*)d_in[7];
    const float* b2    = (const float*)d_in[8];
    const float* b3    = (const float*)d_in[9];
    float* out = (float*)d_out;

    prep_kernel<<<dim3(64), dim3(256), 0, stream>>>(w1, w2, w3);
    fused_kernel<<<dim3(NG16), dim3(256), 0, stream>>>(
        y, erate, Tin, w1, b1, b2, b3, out);
}

// Round 7
// 270.237 us; speedup vs baseline: 1.3979x; 1.0436x over previous
//
#include <hip/hip_runtime.h>
#include <hip/hip_bf16.h>

// NeuralInelasticModel fused fwd + Jacobian, MFMA bf16.
// V12: 32 samples/block, 512 threads (8 waves), 2048 blocks, 2 blocks/CU (LDS ~72KB).
// Each wave owns 2 N-tiles and computes BOTH 16-sample groups against them:
//   - phase-B/C weight loads per sample HALVED (g_w2T/g_w2B fragments reused across groups)
//   - barriers per sample halved (11 per 32 samples vs 22)
//   - launch_bounds(512,4) -> 512-reg/wave budget at the LDS-capped 2 blocks/CU:
//     spill impossible (V9/V11 carried 34MB residual spill-writes at cap 170)
// Carried from V11: XOR bank-swizzle (9.6M->0.96M conflicts), s_setprio around MFMA
// clusters (+2.5%), cy hoist, phase-B unroll 2, separate A2-build phase.
// m1 mask distribution via 2KB LDS array (cross-wave; shuffle no longer reaches).
// Numerics bit-identical to V11 (same ops, same order, per element).

typedef unsigned short ushort_t;
typedef __attribute__((ext_vector_type(8))) short bf16x8;   // 8 bf16 = 4 VGPRs
typedef __attribute__((ext_vector_type(4))) float f32x4;

#define NSAMP (64 * 1024)
#define NG32 (NSAMP / 32)
#define OFF_YDOT 0
#define OFF_DY (NSAMP * 6)
#define OFF_DE (OFF_DY + NSAMP * 36)
#define OFF_DT (OFF_DE + NSAMP * 6)

// Weights repacked into MFMA B-fragment order:
// frag elem idx = ((nt*8 + kt)*64 + lane)*8 + jj,
// value = B[k = kt*32 + (lane>>4)*8 + jj][n = nt*16 + (lane&15)]
__device__ __align__(16) ushort_t g_w2T_hi[65536];   // z2 GEMM: B[k=j][n=h] = w2[h][j]
__device__ __align__(16) ushort_t g_w2T_mid[65536];
__device__ __align__(16) ushort_t g_w2T_lo[65536];
__device__ __align__(16) ushort_t g_w2B[65536];      // B GEMM:  B[k=h][n=j] = w2[h][j]
__device__ __align__(16) ushort_t g_w1e[4096];       // J GEMM:  B[k=j][n=kout] = w1[j][kout] (kout<8 else 0)
__device__ __align__(16) ushort_t g_w3b[1536];       // w3 bf16 row-major [6][256]

static __device__ __forceinline__ ushort_t f2bf(float f) {
    union { __hip_bfloat16 b; ushort_t u; } c;
    c.b = __float2bfloat16(f);
    return c.u;
}
static __device__ __forceinline__ float bf2f(ushort_t u) {
    union { ushort_t u; __hip_bfloat16 b; } c;
    c.u = u;
    return __bfloat162float(c.b);
}

// Bank swizzle for bf16 frag regions (region bases 1KiB-aligned):
// fold byte-addr bits [9:8] into bank bits [6:5]. Involution; 16B-block-preserving.
static __device__ __forceinline__ int swzu(int E) { return E ^ ((E >> 3) & 0x30); }  // ushort idx
static __device__ __forceinline__ int swzo(int o) { return o ^ ((o >> 3) & 0x6); }   // 16B-octet idx

__global__ void prep_kernel(const float* __restrict__ w1, const float* __restrict__ w2,
                            const float* __restrict__ w3) {
    const int gtid = blockIdx.x * blockDim.x + threadIdx.x;
    const int stride = gridDim.x * blockDim.x;
    for (int idx = gtid; idx < 65536; idx += stride) {
        const int nt = idx >> 12, kt = (idx >> 9) & 7, L = (idx >> 3) & 63, jj = idx & 7;
        const int n = nt * 16 + (L & 15);
        const int k = kt * 32 + ((L >> 4) & 3) * 8 + jj;
        const float vT = w2[n * 256 + k];          // w2T: B[k=j][n=h]
        const ushort_t hi = f2bf(vT);
        const float r1 = vT - bf2f(hi);
        const ushort_t mid = f2bf(r1);
        g_w2T_hi[idx]  = hi;
        g_w2T_mid[idx] = mid;
        g_w2T_lo[idx]  = f2bf(r1 - bf2f(mid));
        g_w2B[idx] = f2bf(w2[k * 256 + n]);        // w2B: B[k=h][n=j]
    }
    for (int idx = gtid; idx < 4096; idx += stride) {
        const int kt = idx >> 9, L = (idx >> 3) & 63, jj = idx & 7;
        const int kout = L & 15;
        const int j = kt * 32 + ((L >> 4) & 3) * 8 + jj;
        g_w1e[idx] = (kout < 8) ? f2bf(w1[j * 8 + kout]) : (ushort_t)0;
    }
    for (int idx = gtid; idx < 1536; idx += stride) g_w3b[idx] = f2bf(w3[idx]);
}

// LDS layout (72064 B -> 2 blocks/CU), bf16 frag regions XOR-swizzled, 1KB-aligned bases:
//   [0, 49152)     v1hi [2g][4096 u16] @0 | v1mid @16384 | v1lo @32768. Dead after B.
//                    Post-B alias: A2/Bm [2 g][3 mt][8 kt][64][8] bf16 (2 x 24576 B).
//   [49152, 50176) xs: 32 samples x 8 f32.
//   [50176, 66560) v2B [2 g][8 kt][64][8] bf16; n-dim = sample-in-group; = m2 mask.
//   [66560, 69632) Jsh [2 g][48][8] f32.
//   [69632, 70016) ydsh [2 g][48] f32.
//   [70016, 72064) m1sh [2 g][256] u32 (z1 masks, bit s = sample-in-group).
#define SMEM_BYTES 72064

__global__ __launch_bounds__(512, 4) void fused_kernel(
    const float* __restrict__ y, const float* __restrict__ erate,
    const float* __restrict__ Tin, const float* __restrict__ w1,
    const float* __restrict__ b1, const float* __restrict__ b2,
    const float* __restrict__ b3, float* __restrict__ out)
{
    __shared__ __align__(16) char smem[SMEM_BYTES];
    ushort_t* v1hi  = (ushort_t*)(smem + 0);
    ushort_t* v1mid = (ushort_t*)(smem + 16384);
    ushort_t* v1lo  = (ushort_t*)(smem + 32768);
    ushort_t* A2    = (ushort_t*)(smem + 0);
    float*    xs    = (float*)(smem + 49152);
    ushort_t* v2B   = (ushort_t*)(smem + 50176);
    float*    Jsh   = (float*)(smem + 66560);
    float*    ydsh  = (float*)(smem + 69632);
    unsigned int* m1sh = (unsigned int*)(smem + 70016);

    const int tid  = threadIdx.x;
    const int lane = tid & 63;
    const int wave = tid >> 6;       // 0..7
    const int wg   = wave >> 2;      // group this wave serves in A2/cy/D phases
    const int w4   = wave & 3;       // role within group
    const int l15  = lane & 15;
    const int quad = lane >> 4;
    const int jz   = tid & 255;      // hidden unit for z1
    const int gz   = tid >> 8;       // sample group for z1

    // per-thread weight regs for z1 (thread jz == hidden unit)
    float w1r[8];
#pragma unroll
    for (int k = 0; k < 8; ++k) w1r[k] = w1[jz * 8 + k];
    const float b1r = b1[jz];
    float b2v[2];
#pragma unroll
    for (int n = 0; n < 2; ++n) b2v[n] = b2[(wave * 2 + n) * 16 + l15];

    const int g = blockIdx.x;
    const int s0 = g * 32;

    // ---- stage x for 32 samples ----
    if (tid < 256) {
        const int s = tid >> 3, k = tid & 7;
        float v;
        if (k < 6)       v = y[(s0 + s) * 6 + k];
        else if (k == 6) v = erate[s0 + s];
        else             v = Tin[s0 + s];
        xs[s * 8 + k] = v;
    }
    __syncthreads();  // (0)

    // ---- z1 (exact fp32) + 3-way bf16 split of v1 (A-frag, swizzled) + m1 mask -> LDS ----
    {
        unsigned int m1self = 0;  // bit s = (z1[gz*16+s][jz] > 0)
        const int ktw = jz >> 5, qd = (jz >> 3) & 3, jj = jz & 7;
        const int vb = gz * 4096;  // group region offset (ushorts)
#pragma unroll 4
        for (int s = 0; s < 16; ++s) {
            float z = b1r;
#pragma unroll
            for (int k = 0; k < 8; ++k) z = fmaf(w1r[k], xs[(gz * 16 + s) * 8 + k], z);
            const float v = fmaxf(z, 0.0f);
            m1self |= (v > 0.0f ? 1u : 0u) << s;
            const ushort_t hi = f2bf(v);
            const float r1 = v - bf2f(hi);
            const ushort_t mid = f2bf(r1);
            const int e = vb + swzu((ktw * 64 + (s | (qd << 4))) * 8 + jj);
            v1hi[e]  = hi;
            v1mid[e] = mid;
            v1lo[e]  = f2bf(r1 - bf2f(mid));
        }
        m1sh[tid] = m1self;  // [gz][jz]
    }
    __syncthreads();  // (1) splits + masks visible

    // ---- phase B: z2 = v1 @ w2^T, 3-way split (6 MFMAs), M=32 (2 groups) N=256 K=256 ----
    // Each wave: 2 n-tiles, both groups -> each B-fragment load feeds 2 MFMA sets.
    {
        f32x4 cz[2][2];  // [group][n]
#pragma unroll
        for (int gi = 0; gi < 2; ++gi)
#pragma unroll
            for (int n = 0; n < 2; ++n) cz[gi][n] = (f32x4){0, 0, 0, 0};
#pragma unroll 2
        for (int kt = 0; kt < 8; ++kt) {
            const int ao = swzo(kt * 64 + lane) * 8;
            bf16x8 ahi[2], ami[2], alo[2];
#pragma unroll
            for (int gi = 0; gi < 2; ++gi) {
                ahi[gi] = *(const bf16x8*)&v1hi[gi * 4096 + ao];
                ami[gi] = *(const bf16x8*)&v1mid[gi * 4096 + ao];
                alo[gi] = *(const bf16x8*)&v1lo[gi * 4096 + ao];
            }
#pragma unroll
            for (int n = 0; n < 2; ++n) {
                const int bidx = (((wave * 2 + n) * 8 + kt) * 64 + lane) * 8;
                bf16x8 bh = *(const bf16x8*)&g_w2T_hi[bidx];
                bf16x8 bm = *(const bf16x8*)&g_w2T_mid[bidx];
                bf16x8 bl = *(const bf16x8*)&g_w2T_lo[bidx];
                __builtin_amdgcn_s_setprio(1);
#pragma unroll
                for (int gi = 0; gi < 2; ++gi) {
                    cz[gi][n] = __builtin_amdgcn_mfma_f32_16x16x32_bf16(alo[gi], bh, cz[gi][n], 0, 0, 0);
                    cz[gi][n] = __builtin_amdgcn_mfma_f32_16x16x32_bf16(ami[gi], bm, cz[gi][n], 0, 0, 0);
                    cz[gi][n] = __builtin_amdgcn_mfma_f32_16x16x32_bf16(ahi[gi], bl, cz[gi][n], 0, 0, 0);
                    cz[gi][n] = __builtin_amdgcn_mfma_f32_16x16x32_bf16(ami[gi], bh, cz[gi][n], 0, 0, 0);
                    cz[gi][n] = __builtin_amdgcn_mfma_f32_16x16x32_bf16(ahi[gi], bm, cz[gi][n], 0, 0, 0);
                    cz[gi][n] = __builtin_amdgcn_mfma_f32_16x16x32_bf16(ahi[gi], bh, cz[gi][n], 0, 0, 0);
                }
                __builtin_amdgcn_s_setprio(0);
            }
        }
        // epilogue: v2 = relu(z2 + b2) -> v2B (B-frag layout, n=sample-in-group; = m2)
#pragma unroll
        for (int n = 0; n < 2; ++n) {
            const int h = (wave * 2 + n) * 16 + l15;
            const int ktd = h >> 5, qd = (h >> 3) & 3, jj = h & 7;
#pragma unroll
            for (int gi = 0; gi < 2; ++gi) {
#pragma unroll
                for (int r = 0; r < 4; ++r) {
                    const int s = quad * 4 + r;  // C layout: row = quad*4 + reg
                    const float v2 = fmaxf(cz[gi][n][r] + b2v[n], 0.0f);
                    v2B[gi * 4096 + swzu((ktd * 64 + (s | (qd << 4))) * 8 + jj)] = f2bf(v2);
                }
            }
        }
    }
    __syncthreads();  // (2) v2B visible; all v1 reads done -> A2 region writable

    // ---- chunks: per iteration, each group's chunk c handled in parallel ----
#pragma unroll 1
    for (int c = 0; c < 2; ++c) {
        // build A2[g][m = sl*6+i][h] = m2[g][sg][h] ? w3[i][h] : 0 (waves 0-2 g0, 4-6 g1)
        if (w4 < 3) {
            const int mt = w4;
            const int m = mt * 16 + l15;
            const int sl = m / 6, i = m - sl * 6;
            const int sg = c * 8 + sl;
#pragma unroll 2
            for (int kt = 0; kt < 8; ++kt) {
                bf16x8 vv = *(const bf16x8*)&v2B[wg * 4096 + swzo(kt * 64 + (sg | (quad << 4))) * 8];
                bf16x8 wv = *(const bf16x8*)&g_w3b[i * 256 + kt * 32 + quad * 8];
                bf16x8 o;
#pragma unroll
                for (int e = 0; e < 8; ++e)
                    o[e] = ((ushort_t)vv[e] != 0) ? wv[e] : (short)0;
                *(bf16x8*)&A2[wg * 12288 + swzo((mt * 8 + kt) * 64 + lane) * 8] = o;
            }
        }
        __syncthreads();  // (3) A2 visible

        // ydot tiles: wave 3 -> group 0, wave 7 -> group 1 (short; cy dies before cc loop)
        if (w4 == 3) {
            f32x4 cy[3];
#pragma unroll
            for (int mt = 0; mt < 3; ++mt) cy[mt] = (f32x4){0, 0, 0, 0};
#pragma unroll 2
            for (int kt = 0; kt < 8; ++kt) {
                bf16x8 bv = *(const bf16x8*)&v2B[wg * 4096 + swzo(kt * 64 + lane) * 8];
                __builtin_amdgcn_s_setprio(1);
#pragma unroll
                for (int mt = 0; mt < 3; ++mt) {
                    bf16x8 a = *(const bf16x8*)&A2[wg * 12288 + swzo((mt * 8 + kt) * 64 + lane) * 8];
                    cy[mt] = __builtin_amdgcn_mfma_f32_16x16x32_bf16(a, bv, cy[mt], 0, 0, 0);
                }
                __builtin_amdgcn_s_setprio(0);
            }
#pragma unroll
            for (int mt = 0; mt < 3; ++mt) {
#pragma unroll
                for (int r = 0; r < 4; ++r) {
                    const int m = mt * 16 + quad * 4 + r;
                    const int sl = m / 6, i = m - sl * 6;
                    if (l15 == c * 8 + sl) ydsh[wg * 48 + m] = cy[mt][r] + b3[i];
                }
            }
        }

        // phase C: B = A2 @ w2, M=96 (2 groups x 48) N=256 K=256; wave: 2 n-tiles x both groups
        f32x4 cc[2][3][2];  // [group][mt][n]
#pragma unroll
        for (int gi = 0; gi < 2; ++gi)
#pragma unroll
            for (int mt = 0; mt < 3; ++mt)
#pragma unroll
                for (int n = 0; n < 2; ++n) cc[gi][mt][n] = (f32x4){0, 0, 0, 0};
#pragma unroll 2
        for (int kt = 0; kt < 8; ++kt) {
            bf16x8 a[2][3];
#pragma unroll
            for (int gi = 0; gi < 2; ++gi)
#pragma unroll
                for (int mt = 0; mt < 3; ++mt)
                    a[gi][mt] = *(const bf16x8*)&A2[gi * 12288 + swzo((mt * 8 + kt) * 64 + lane) * 8];
#pragma unroll
            for (int n = 0; n < 2; ++n) {
                bf16x8 b = *(const bf16x8*)&g_w2B[(((wave * 2 + n) * 8 + kt) * 64 + lane) * 8];
                __builtin_amdgcn_s_setprio(1);
#pragma unroll
                for (int gi = 0; gi < 2; ++gi)
#pragma unroll
                    for (int mt = 0; mt < 3; ++mt)
                        cc[gi][mt][n] = __builtin_amdgcn_mfma_f32_16x16x32_bf16(a[gi][mt], b, cc[gi][mt][n], 0, 0, 0);
                __builtin_amdgcn_s_setprio(0);
            }
        }
        __syncthreads();  // (4) all A2 reads complete before Bm overwrites

        // Bm = (B .* m1) -> bf16 back into A2 region. Mask via m1sh (cross-wave).
#pragma unroll
        for (int gi = 0; gi < 2; ++gi) {
#pragma unroll
            for (int n = 0; n < 2; ++n) {
                const int j = (wave * 2 + n) * 16 + l15;  // C layout: col = lane&15
                const unsigned int mcol = m1sh[gi * 256 + j];
                const int ktd = j >> 5, qd = (j >> 3) & 3, jjd = j & 7;
#pragma unroll
                for (int mt = 0; mt < 3; ++mt) {
#pragma unroll
                    for (int r = 0; r < 4; ++r) {
                        const int m = mt * 16 + quad * 4 + r;  // C layout: row = quad*4+reg
                        const int sg = c * 8 + m / 6;
                        const ushort_t bm =
                            ((mcol >> sg) & 1u) ? f2bf(cc[gi][mt][n][r]) : (ushort_t)0;
                        A2[gi * 12288 + swzu(((mt * 8 + ktd) * 64 + ((m & 15) | (qd << 4))) * 8 + jjd)] = bm;
                    }
                }
            }
        }
        __syncthreads();  // (5) Bm visible

        // phase D: J = Bm @ w1e, per group M=48 N=16 K=256; waves 0-2 (g0), 4-6 (g1)
        if (w4 < 3) {
            f32x4 dc = {0, 0, 0, 0};
#pragma unroll 2
            for (int kt = 0; kt < 8; ++kt) {
                bf16x8 a = *(const bf16x8*)&A2[wg * 12288 + swzo((w4 * 8 + kt) * 64 + lane) * 8];
                bf16x8 b = *(const bf16x8*)&g_w1e[(kt * 64 + lane) * 8];
                dc = __builtin_amdgcn_mfma_f32_16x16x32_bf16(a, b, dc, 0, 0, 0);
            }
            if (l15 < 8) {
#pragma unroll
                for (int r = 0; r < 4; ++r) {
                    const int m = w4 * 16 + quad * 4 + r;
                    Jsh[(wg * 48 + m) * 8 + l15] = dc[r];
                }
            }
        }
        __syncthreads();  // (6) Jsh/ydsh visible; all Bm reads done -> next chunk may overwrite

        // coalesced output: each group's 256 threads write that group's 8 samples
        {
            const int tg = tid & 255;
            const int s0c = s0 + gz * 16 + c * 8;
            const long base6 = (long)s0c * 6;
            {
                const int u = tg;  // dy dwords 0..255
                const int s = u / 36, rem = u - s * 36, ii = rem / 6, jy = rem - ii * 6;
                out[OFF_DY + (long)s0c * 36 + u] = Jsh[(gz * 48 + s * 6 + ii) * 8 + jy];
            }
            if (tg < 32) {  // dy dwords 256..287
                const int u = 256 + tg;
                const int s = u / 36, rem = u - s * 36, ii = rem / 6, jy = rem - ii * 6;
                out[OFF_DY + (long)s0c * 36 + u] = Jsh[(gz * 48 + s * 6 + ii) * 8 + jy];
            }
            if (tg < 48) out[OFF_YDOT + base6 + tg] = ydsh[gz * 48 + tg];
            const int t2 = tg - 64;
            if (t2 >= 0 && t2 < 48) out[OFF_DE + base6 + t2] = Jsh[(gz * 48 + t2) * 8 + 6];
            const int t3 = tg - 128;
            if (t3 >= 0 && t3 < 48) out[OFF_DT + base6 + t3] = Jsh[(gz * 48 + t3) * 8 + 7];
        }
    }
}

extern "C" void kernel_launch(void* const* d_in, const int* in_sizes, int n_in,
                              void* d_out, int out_size, void* d_ws, size_t ws_size,
                              hipStream_t stream) {
    // setup_inputs order: t(0,unused), y(1), erate(2), T(3), w1(4), w2(5), w3(6), b1(7), b2(8), b3(9)
    const float* y     = (const float*)d_in[1];
    const float* erate = (const float*)d_in[2];
    const float* Tin   = (const float*)d_in[3];
    const float* w1    = (const float*)d_in[4];
    const float* w2    = (const float*)d_in[5];
    const float* w3    = (const float*)d_in[6];
    const float* b1    = (const float*)d_in[7];
    const float* b2    = (const float*)d_in[8];
    const float* b3    = (const float*)d_in[9];
    float* out = (float*)d_out;

    prep_kernel<<<dim3(64), dim3(256), 0, stream>>>(w1, w2, w3);
    fused_kernel<<<dim3(NG32), dim3(512), 0, stream>>>(
        y, erate, Tin, w1, b1, b2, b3, out);
}

// Round 8
// 237.432 us; speedup vs baseline: 1.5911x; 1.1382x over previous
//
#include <hip/hip_runtime.h>
#include <hip/hip_bf16.h>

// NeuralInelasticModel fused fwd + Jacobian, MFMA bf16.
// V13: 32 samples/block, 512 threads (8 waves), 2048 blocks, 2 blocks/CU (LDS ~72KB).
// V12 lesson: reported VGPR_Count EXCLUDES accumulators; real totals: R3/R6 = 84+64 = 148,
// R5/R7 = 64+64 = 128 (= cap, spilling the ~20-reg excess). (512,4) cap = 128 total.
// V13 = V12 + demand cut to fit 128:
//   (a) phase C split by GROUP (sequential gi passes, unroll 1): live acc 48 -> 24;
//       Bm(gi) written right after each pass's barrier (+1 barrier/chunk).
//       b-frags re-read by pass 2 (L2-hot); phase-B 3x-weight reuse untouched.
//   (b) phase-B kt unroll 2 -> 1 (halves in-flight b-frag transient regs).
// Carried: XOR bank-swizzle, s_setprio on MFMA clusters, cy hoist, LDS m1 masks.
// Numerics bit-identical (same per-element op order).

typedef unsigned short ushort_t;
typedef __attribute__((ext_vector_type(8))) short bf16x8;   // 8 bf16 = 4 VGPRs
typedef __attribute__((ext_vector_type(4))) float f32x4;

#define NSAMP (64 * 1024)
#define NG32 (NSAMP / 32)
#define OFF_YDOT 0
#define OFF_DY (NSAMP * 6)
#define OFF_DE (OFF_DY + NSAMP * 36)
#define OFF_DT (OFF_DE + NSAMP * 6)

// Weights repacked into MFMA B-fragment order:
// frag elem idx = ((nt*8 + kt)*64 + lane)*8 + jj,
// value = B[k = kt*32 + (lane>>4)*8 + jj][n = nt*16 + (lane&15)]
__device__ __align__(16) ushort_t g_w2T_hi[65536];   // z2 GEMM: B[k=j][n=h] = w2[h][j]
__device__ __align__(16) ushort_t g_w2T_mid[65536];
__device__ __align__(16) ushort_t g_w2T_lo[65536];
__device__ __align__(16) ushort_t g_w2B[65536];      // B GEMM:  B[k=h][n=j] = w2[h][j]
__device__ __align__(16) ushort_t g_w1e[4096];       // J GEMM:  B[k=j][n=kout] = w1[j][kout] (kout<8 else 0)
__device__ __align__(16) ushort_t g_w3b[1536];       // w3 bf16 row-major [6][256]

static __device__ __forceinline__ ushort_t f2bf(float f) {
    union { __hip_bfloat16 b; ushort_t u; } c;
    c.b = __float2bfloat16(f);
    return c.u;
}
static __device__ __forceinline__ float bf2f(ushort_t u) {
    union { ushort_t u; __hip_bfloat16 b; } c;
    c.u = u;
    return __bfloat162float(c.b);
}

// Bank swizzle for bf16 frag regions (region bases 1KiB-aligned):
// fold byte-addr bits [9:8] into bank bits [6:5]. Involution; 16B-block-preserving.
static __device__ __forceinline__ int swzu(int E) { return E ^ ((E >> 3) & 0x30); }  // ushort idx
static __device__ __forceinline__ int swzo(int o) { return o ^ ((o >> 3) & 0x6); }   // 16B-octet idx

__global__ void prep_kernel(const float* __restrict__ w1, const float* __restrict__ w2,
                            const float* __restrict__ w3) {
    const int gtid = blockIdx.x * blockDim.x + threadIdx.x;
    const int stride = gridDim.x * blockDim.x;
    for (int idx = gtid; idx < 65536; idx += stride) {
        const int nt = idx >> 12, kt = (idx >> 9) & 7, L = (idx >> 3) & 63, jj = idx & 7;
        const int n = nt * 16 + (L & 15);
        const int k = kt * 32 + ((L >> 4) & 3) * 8 + jj;
        const float vT = w2[n * 256 + k];          // w2T: B[k=j][n=h]
        const ushort_t hi = f2bf(vT);
        const float r1 = vT - bf2f(hi);
        const ushort_t mid = f2bf(r1);
        g_w2T_hi[idx]  = hi;
        g_w2T_mid[idx] = mid;
        g_w2T_lo[idx]  = f2bf(r1 - bf2f(mid));
        g_w2B[idx] = f2bf(w2[k * 256 + n]);        // w2B: B[k=h][n=j]
    }
    for (int idx = gtid; idx < 4096; idx += stride) {
        const int kt = idx >> 9, L = (idx >> 3) & 63, jj = idx & 7;
        const int kout = L & 15;
        const int j = kt * 32 + ((L >> 4) & 3) * 8 + jj;
        g_w1e[idx] = (kout < 8) ? f2bf(w1[j * 8 + kout]) : (ushort_t)0;
    }
    for (int idx = gtid; idx < 1536; idx += stride) g_w3b[idx] = f2bf(w3[idx]);
}

// LDS layout (72064 B -> 2 blocks/CU), bf16 frag regions XOR-swizzled, 1KB-aligned bases:
//   [0, 49152)     v1hi [2g][4096 u16] @0 | v1mid @16384 | v1lo @32768. Dead after B.
//                    Post-B alias: A2/Bm [2 g][3 mt][8 kt][64][8] bf16 (2 x 24576 B).
//   [49152, 50176) xs: 32 samples x 8 f32.
//   [50176, 66560) v2B [2 g][8 kt][64][8] bf16; n-dim = sample-in-group; = m2 mask.
//   [66560, 69632) Jsh [2 g][48][8] f32.
//   [69632, 70016) ydsh [2 g][48] f32.
//   [70016, 72064) m1sh [2 g][256] u32 (z1 masks, bit s = sample-in-group).
#define SMEM_BYTES 72064

__global__ __launch_bounds__(512, 4) void fused_kernel(
    const float* __restrict__ y, const float* __restrict__ erate,
    const float* __restrict__ Tin, const float* __restrict__ w1,
    const float* __restrict__ b1, const float* __restrict__ b2,
    const float* __restrict__ b3, float* __restrict__ out)
{
    __shared__ __align__(16) char smem[SMEM_BYTES];
    ushort_t* v1hi  = (ushort_t*)(smem + 0);
    ushort_t* v1mid = (ushort_t*)(smem + 16384);
    ushort_t* v1lo  = (ushort_t*)(smem + 32768);
    ushort_t* A2    = (ushort_t*)(smem + 0);
    float*    xs    = (float*)(smem + 49152);
    ushort_t* v2B   = (ushort_t*)(smem + 50176);
    float*    Jsh   = (float*)(smem + 66560);
    float*    ydsh  = (float*)(smem + 69632);
    unsigned int* m1sh = (unsigned int*)(smem + 70016);

    const int tid  = threadIdx.x;
    const int lane = tid & 63;
    const int wave = tid >> 6;       // 0..7
    const int wg   = wave >> 2;      // group this wave serves in A2/cy/D phases
    const int w4   = wave & 3;       // role within group
    const int l15  = lane & 15;
    const int quad = lane >> 4;
    const int jz   = tid & 255;      // hidden unit for z1
    const int gz   = tid >> 8;       // sample group for z1

    // per-thread weight regs for z1 (thread jz == hidden unit)
    float w1r[8];
#pragma unroll
    for (int k = 0; k < 8; ++k) w1r[k] = w1[jz * 8 + k];
    const float b1r = b1[jz];
    float b2v[2];
#pragma unroll
    for (int n = 0; n < 2; ++n) b2v[n] = b2[(wave * 2 + n) * 16 + l15];

    const int g = blockIdx.x;
    const int s0 = g * 32;

    // ---- stage x for 32 samples ----
    if (tid < 256) {
        const int s = tid >> 3, k = tid & 7;
        float v;
        if (k < 6)       v = y[(s0 + s) * 6 + k];
        else if (k == 6) v = erate[s0 + s];
        else             v = Tin[s0 + s];
        xs[s * 8 + k] = v;
    }
    __syncthreads();  // (0)

    // ---- z1 (exact fp32) + 3-way bf16 split of v1 (A-frag, swizzled) + m1 mask -> LDS ----
    {
        unsigned int m1self = 0;  // bit s = (z1[gz*16+s][jz] > 0)
        const int ktw = jz >> 5, qd = (jz >> 3) & 3, jj = jz & 7;
        const int vb = gz * 4096;  // group region offset (ushorts)
#pragma unroll 4
        for (int s = 0; s < 16; ++s) {
            float z = b1r;
#pragma unroll
            for (int k = 0; k < 8; ++k) z = fmaf(w1r[k], xs[(gz * 16 + s) * 8 + k], z);
            const float v = fmaxf(z, 0.0f);
            m1self |= (v > 0.0f ? 1u : 0u) << s;
            const ushort_t hi = f2bf(v);
            const float r1 = v - bf2f(hi);
            const ushort_t mid = f2bf(r1);
            const int e = vb + swzu((ktw * 64 + (s | (qd << 4))) * 8 + jj);
            v1hi[e]  = hi;
            v1mid[e] = mid;
            v1lo[e]  = f2bf(r1 - bf2f(mid));
        }
        m1sh[tid] = m1self;  // [gz][jz]
    }
    __syncthreads();  // (1) splits + masks visible

    // ---- phase B: z2 = v1 @ w2^T, 3-way split (6 MFMAs), M=32 (2 groups) N=256 K=256 ----
    // Each wave: 2 n-tiles, both groups -> each B-fragment load feeds 2 MFMA sets.
    // kt unroll 1: halves in-flight b-frag transient regs (demand must fit 128 total).
    {
        f32x4 cz[2][2];  // [group][n]
#pragma unroll
        for (int gi = 0; gi < 2; ++gi)
#pragma unroll
            for (int n = 0; n < 2; ++n) cz[gi][n] = (f32x4){0, 0, 0, 0};
#pragma unroll 1
        for (int kt = 0; kt < 8; ++kt) {
            const int ao = swzo(kt * 64 + lane) * 8;
            bf16x8 ahi[2], ami[2], alo[2];
#pragma unroll
            for (int gi = 0; gi < 2; ++gi) {
                ahi[gi] = *(const bf16x8*)&v1hi[gi * 4096 + ao];
                ami[gi] = *(const bf16x8*)&v1mid[gi * 4096 + ao];
                alo[gi] = *(const bf16x8*)&v1lo[gi * 4096 + ao];
            }
#pragma unroll
            for (int n = 0; n < 2; ++n) {
                const int bidx = (((wave * 2 + n) * 8 + kt) * 64 + lane) * 8;
                bf16x8 bh = *(const bf16x8*)&g_w2T_hi[bidx];
                bf16x8 bm = *(const bf16x8*)&g_w2T_mid[bidx];
                bf16x8 bl = *(const bf16x8*)&g_w2T_lo[bidx];
                __builtin_amdgcn_s_setprio(1);
#pragma unroll
                for (int gi = 0; gi < 2; ++gi) {
                    cz[gi][n] = __builtin_amdgcn_mfma_f32_16x16x32_bf16(alo[gi], bh, cz[gi][n], 0, 0, 0);
                    cz[gi][n] = __builtin_amdgcn_mfma_f32_16x16x32_bf16(ami[gi], bm, cz[gi][n], 0, 0, 0);
                    cz[gi][n] = __builtin_amdgcn_mfma_f32_16x16x32_bf16(ahi[gi], bl, cz[gi][n], 0, 0, 0);
                    cz[gi][n] = __builtin_amdgcn_mfma_f32_16x16x32_bf16(ami[gi], bh, cz[gi][n], 0, 0, 0);
                    cz[gi][n] = __builtin_amdgcn_mfma_f32_16x16x32_bf16(ahi[gi], bm, cz[gi][n], 0, 0, 0);
                    cz[gi][n] = __builtin_amdgcn_mfma_f32_16x16x32_bf16(ahi[gi], bh, cz[gi][n], 0, 0, 0);
                }
                __builtin_amdgcn_s_setprio(0);
            }
        }
        // epilogue: v2 = relu(z2 + b2) -> v2B (B-frag layout, n=sample-in-group; = m2)
#pragma unroll
        for (int n = 0; n < 2; ++n) {
            const int h = (wave * 2 + n) * 16 + l15;
            const int ktd = h >> 5, qd = (h >> 3) & 3, jj = h & 7;
#pragma unroll
            for (int gi = 0; gi < 2; ++gi) {
#pragma unroll
                for (int r = 0; r < 4; ++r) {
                    const int s = quad * 4 + r;  // C layout: row = quad*4 + reg
                    const float v2 = fmaxf(cz[gi][n][r] + b2v[n], 0.0f);
                    v2B[gi * 4096 + swzu((ktd * 64 + (s | (qd << 4))) * 8 + jj)] = f2bf(v2);
                }
            }
        }
    }
    __syncthreads();  // (2) v2B visible; all v1 reads done -> A2 region writable

    // ---- chunks: per iteration, each group's chunk c handled in parallel ----
#pragma unroll 1
    for (int c = 0; c < 2; ++c) {
        // build A2[g][m = sl*6+i][h] = m2[g][sg][h] ? w3[i][h] : 0 (waves 0-2 g0, 4-6 g1)
        if (w4 < 3) {
            const int mt = w4;
            const int m = mt * 16 + l15;
            const int sl = m / 6, i = m - sl * 6;
            const int sg = c * 8 + sl;
#pragma unroll 2
            for (int kt = 0; kt < 8; ++kt) {
                bf16x8 vv = *(const bf16x8*)&v2B[wg * 4096 + swzo(kt * 64 + (sg | (quad << 4))) * 8];
                bf16x8 wv = *(const bf16x8*)&g_w3b[i * 256 + kt * 32 + quad * 8];
                bf16x8 o;
#pragma unroll
                for (int e = 0; e < 8; ++e)
                    o[e] = ((ushort_t)vv[e] != 0) ? wv[e] : (short)0;
                *(bf16x8*)&A2[wg * 12288 + swzo((mt * 8 + kt) * 64 + lane) * 8] = o;
            }
        }
        __syncthreads();  // (3) A2 visible

        // ydot tiles: wave 3 -> group 0, wave 7 -> group 1 (short; cy dies before cc loops)
        if (w4 == 3) {
            f32x4 cy[3];
#pragma unroll
            for (int mt = 0; mt < 3; ++mt) cy[mt] = (f32x4){0, 0, 0, 0};
#pragma unroll 2
            for (int kt = 0; kt < 8; ++kt) {
                bf16x8 bv = *(const bf16x8*)&v2B[wg * 4096 + swzo(kt * 64 + lane) * 8];
                __builtin_amdgcn_s_setprio(1);
#pragma unroll
                for (int mt = 0; mt < 3; ++mt) {
                    bf16x8 a = *(const bf16x8*)&A2[wg * 12288 + swzo((mt * 8 + kt) * 64 + lane) * 8];
                    cy[mt] = __builtin_amdgcn_mfma_f32_16x16x32_bf16(a, bv, cy[mt], 0, 0, 0);
                }
                __builtin_amdgcn_s_setprio(0);
            }
#pragma unroll
            for (int mt = 0; mt < 3; ++mt) {
#pragma unroll
                for (int r = 0; r < 4; ++r) {
                    const int m = mt * 16 + quad * 4 + r;
                    const int sl = m / 6, i = m - sl * 6;
                    if (l15 == c * 8 + sl) ydsh[wg * 48 + m] = cy[mt][r] + b3[i];
                }
            }
        }

        // phase C split by GROUP: pass gi computes B(gi) = A2[gi] @ w2 (M=48 N=256 K=256),
        // then (after the A2[gi]-read barrier) masks to Bm(gi) in place.
        // Live acc = 24 regs (was 48). Pass 2 re-reads the same b-frags (L2-hot).
#pragma unroll 1
        for (int gi = 0; gi < 2; ++gi) {
            f32x4 cc[3][2];  // [mt][n]
#pragma unroll
            for (int mt = 0; mt < 3; ++mt)
#pragma unroll
                for (int n = 0; n < 2; ++n) cc[mt][n] = (f32x4){0, 0, 0, 0};
#pragma unroll 2
            for (int kt = 0; kt < 8; ++kt) {
                bf16x8 a[3];
#pragma unroll
                for (int mt = 0; mt < 3; ++mt)
                    a[mt] = *(const bf16x8*)&A2[gi * 12288 + swzo((mt * 8 + kt) * 64 + lane) * 8];
#pragma unroll
                for (int n = 0; n < 2; ++n) {
                    bf16x8 b = *(const bf16x8*)&g_w2B[(((wave * 2 + n) * 8 + kt) * 64 + lane) * 8];
                    __builtin_amdgcn_s_setprio(1);
#pragma unroll
                    for (int mt = 0; mt < 3; ++mt)
                        cc[mt][n] = __builtin_amdgcn_mfma_f32_16x16x32_bf16(a[mt], b, cc[mt][n], 0, 0, 0);
                    __builtin_amdgcn_s_setprio(0);
                }
            }
            __syncthreads();  // (4.gi) all A2[gi] reads complete before Bm(gi) overwrites

            // Bm(gi) = (B .* m1) -> bf16 back into A2[gi]. Mask via m1sh (cross-wave).
#pragma unroll
            for (int n = 0; n < 2; ++n) {
                const int j = (wave * 2 + n) * 16 + l15;  // C layout: col = lane&15
                const unsigned int mcol = m1sh[gi * 256 + j];
                const int ktd = j >> 5, qd = (j >> 3) & 3, jjd = j & 7;
#pragma unroll
                for (int mt = 0; mt < 3; ++mt) {
#pragma unroll
                    for (int r = 0; r < 4; ++r) {
                        const int m = mt * 16 + quad * 4 + r;  // C layout: row = quad*4+reg
                        const int sg = c * 8 + m / 6;
                        const ushort_t bm =
                            ((mcol >> sg) & 1u) ? f2bf(cc[mt][n][r]) : (ushort_t)0;
                        A2[gi * 12288 + swzu(((mt * 8 + ktd) * 64 + ((m & 15) | (qd << 4))) * 8 + jjd)] = bm;
                    }
                }
            }
        }
        __syncthreads();  // (5) Bm both groups visible

        // phase D: J = Bm @ w1e, per group M=48 N=16 K=256; waves 0-2 (g0), 4-6 (g1)
        if (w4 < 3) {
            f32x4 dc = {0, 0, 0, 0};
#pragma unroll 2
            for (int kt = 0; kt < 8; ++kt) {
                bf16x8 a = *(const bf16x8*)&A2[wg * 12288 + swzo((w4 * 8 + kt) * 64 + lane) * 8];
                bf16x8 b = *(const bf16x8*)&g_w1e[(kt * 64 + lane) * 8];
                dc = __builtin_amdgcn_mfma_f32_16x16x32_bf16(a, b, dc, 0, 0, 0);
            }
            if (l15 < 8) {
#pragma unroll
                for (int r = 0; r < 4; ++r) {
                    const int m = w4 * 16 + quad * 4 + r;
                    Jsh[(wg * 48 + m) * 8 + l15] = dc[r];
                }
            }
        }
        __syncthreads();  // (6) Jsh/ydsh visible; all Bm reads done -> next chunk may overwrite

        // coalesced output: each group's 256 threads write that group's 8 samples
        {
            const int tg = tid & 255;
            const int s0c = s0 + gz * 16 + c * 8;
            const long base6 = (long)s0c * 6;
            {
                const int u = tg;  // dy dwords 0..255
                const int s = u / 36, rem = u - s * 36, ii = rem / 6, jy = rem - ii * 6;
                out[OFF_DY + (long)s0c * 36 + u] = Jsh[(gz * 48 + s * 6 + ii) * 8 + jy];
            }
            if (tg < 32) {  // dy dwords 256..287
                const int u = 256 + tg;
                const int s = u / 36, rem = u - s * 36, ii = rem / 6, jy = rem - ii * 6;
                out[OFF_DY + (long)s0c * 36 + u] = Jsh[(gz * 48 + s * 6 + ii) * 8 + jy];
            }
            if (tg < 48) out[OFF_YDOT + base6 + tg] = ydsh[gz * 48 + tg];
            const int t2 = tg - 64;
            if (t2 >= 0 && t2 < 48) out[OFF_DE + base6 + t2] = Jsh[(gz * 48 + t2) * 8 + 6];
            const int t3 = tg - 128;
            if (t3 >= 0 && t3 < 48) out[OFF_DT + base6 + t3] = Jsh[(gz * 48 + t3) * 8 + 7];
        }
    }
}

extern "C" void kernel_launch(void* const* d_in, const int* in_sizes, int n_in,
                              void* d_out, int out_size, void* d_ws, size_t ws_size,
                              hipStream_t stream) {
    // setup_inputs order: t(0,unused), y(1), erate(2), T(3), w1(4), w2(5), w3(6), b1(7), b2(8), b3(9)
    const float* y     = (const float*)d_in[1];
    const float* erate = (const float*)d_in[2];
    const float* Tin   = (const float*)d_in[3];
    const float* w1    = (const float*)d_in[4];
    const float* w2    = (const float*)d_in[5];
    const float* w3    = (const float*)d_in[6];
    const float* b1    = (const float*)d_in[7];
    const float* b2    = (const float*)d_in[8];
    const float* b3    = (const float*)d_in[9];
    float* out = (float*)d_out;

    prep_kernel<<<dim3(64), dim3(256), 0, stream>>>(w1, w2, w3);
    fused_kernel<<<dim3(NG32), dim3(512), 0, stream>>>(
        y, erate, Tin, w1, b1, b2, b3, out);
}

// Round 11
// 235.884 us; speedup vs baseline: 1.6015x; 1.0066x over previous
//
#include <hip/hip_runtime.h>
#include <hip/hip_bf16.h>

// NeuralInelasticModel fused fwd + Jacobian, MFMA bf16.
// V15 (resubmit; R10 was an infra failure -- container died, kernel never benched):
// 32 samples/block, 512 threads (8 waves), 2048 blocks, 2 blocks/CU (LDS ~72KB).
// Register model (measured R3-R8): waves/SIMD x (archVGPR + accVGPR) <= 512;
// reported VGPR_Count EXCLUDES acc. (512,4) cap = 128 total; V13 demand ~147 -> 19dw spill.
// V15 = V13 + unroll 2 -> 1 on phase-C kt / A2-build / cy / phase-D loops (halve
//   transient fragment windows; TLP at 4 waves/SIMD covers the lost ILP).
// R9 FAILURE LESSON: hand-written VOP3P asm (v_pk_ashrrev_i16 with literal 15) does NOT
//   replicate inline constants to both 16-bit halves -> hi-lane shift was 0 -> corrupted
//   A2 (absmax 1.64). A2 build reverted to the known-good ternary select. If packed-math
//   is retried, use C ext-vector ops (compiler replicates constants), never asm.
// Carried: XOR bank-swizzle, s_setprio on MFMA clusters, cy hoist, LDS m1 masks,
// phase C split by group (acc 24), phase-B unroll 1.
// Numerics bit-identical to V13 (same per-element op order and select values).

typedef unsigned short ushort_t;
typedef __attribute__((ext_vector_type(8))) short bf16x8;   // 8 bf16 = 4 VGPRs
typedef __attribute__((ext_vector_type(4))) float f32x4;

#define NSAMP (64 * 1024)
#define NG32 (NSAMP / 32)
#define OFF_YDOT 0
#define OFF_DY (NSAMP * 6)
#define OFF_DE (OFF_DY + NSAMP * 36)
#define OFF_DT (OFF_DE + NSAMP * 6)

// Weights repacked into MFMA B-fragment order:
// frag elem idx = ((nt*8 + kt)*64 + lane)*8 + jj,
// value = B[k = kt*32 + (lane>>4)*8 + jj][n = nt*16 + (lane&15)]
__device__ __align__(16) ushort_t g_w2T_hi[65536];   // z2 GEMM: B[k=j][n=h] = w2[h][j]
__device__ __align__(16) ushort_t g_w2T_mid[65536];
__device__ __align__(16) ushort_t g_w2T_lo[65536];
__device__ __align__(16) ushort_t g_w2B[65536];      // B GEMM:  B[k=h][n=j] = w2[h][j]
__device__ __align__(16) ushort_t g_w1e[4096];       // J GEMM:  B[k=j][n=kout] = w1[j][kout] (kout<8 else 0)
__device__ __align__(16) ushort_t g_w3b[1536];       // w3 bf16 row-major [6][256]

static __device__ __forceinline__ ushort_t f2bf(float f) {
    union { __hip_bfloat16 b; ushort_t u; } c;
    c.b = __float2bfloat16(f);
    return c.u;
}
static __device__ __forceinline__ float bf2f(ushort_t u) {
    union { ushort_t u; __hip_bfloat16 b; } c;
    c.u = u;
    return __bfloat162float(c.b);
}

// Bank swizzle for bf16 frag regions (region bases 1KiB-aligned):
// fold byte-addr bits [9:8] into bank bits [6:5]. Involution; 16B-block-preserving.
static __device__ __forceinline__ int swzu(int E) { return E ^ ((E >> 3) & 0x30); }  // ushort idx
static __device__ __forceinline__ int swzo(int o) { return o ^ ((o >> 3) & 0x6); }   // 16B-octet idx

__global__ void prep_kernel(const float* __restrict__ w1, const float* __restrict__ w2,
                            const float* __restrict__ w3) {
    const int gtid = blockIdx.x * blockDim.x + threadIdx.x;
    const int stride = gridDim.x * blockDim.x;
    for (int idx = gtid; idx < 65536; idx += stride) {
        const int nt = idx >> 12, kt = (idx >> 9) & 7, L = (idx >> 3) & 63, jj = idx & 7;
        const int n = nt * 16 + (L & 15);
        const int k = kt * 32 + ((L >> 4) & 3) * 8 + jj;
        const float vT = w2[n * 256 + k];          // w2T: B[k=j][n=h]
        const ushort_t hi = f2bf(vT);
        const float r1 = vT - bf2f(hi);
        const ushort_t mid = f2bf(r1);
        g_w2T_hi[idx]  = hi;
        g_w2T_mid[idx] = mid;
        g_w2T_lo[idx]  = f2bf(r1 - bf2f(mid));
        g_w2B[idx] = f2bf(w2[k * 256 + n]);        // w2B: B[k=h][n=j]
    }
    for (int idx = gtid; idx < 4096; idx += stride) {
        const int kt = idx >> 9, L = (idx >> 3) & 63, jj = idx & 7;
        const int kout = L & 15;
        const int j = kt * 32 + ((L >> 4) & 3) * 8 + jj;
        g_w1e[idx] = (kout < 8) ? f2bf(w1[j * 8 + kout]) : (ushort_t)0;
    }
    for (int idx = gtid; idx < 1536; idx += stride) g_w3b[idx] = f2bf(w3[idx]);
}

// LDS layout (72064 B -> 2 blocks/CU), bf16 frag regions XOR-swizzled, 1KB-aligned bases:
//   [0, 49152)     v1hi [2g][4096 u16] @0 | v1mid @16384 | v1lo @32768. Dead after B.
//                    Post-B alias: A2/Bm [2 g][3 mt][8 kt][64][8] bf16 (2 x 24576 B).
//   [49152, 50176) xs: 32 samples x 8 f32.
//   [50176, 66560) v2B [2 g][8 kt][64][8] bf16; n-dim = sample-in-group; = m2 mask.
//   [66560, 69632) Jsh [2 g][48][8] f32.
//   [69632, 70016) ydsh [2 g][48] f32.
//   [70016, 72064) m1sh [2 g][256] u32 (z1 masks, bit s = sample-in-group).
#define SMEM_BYTES 72064

__global__ __launch_bounds__(512, 4) void fused_kernel(
    const float* __restrict__ y, const float* __restrict__ erate,
    const float* __restrict__ Tin, const float* __restrict__ w1,
    const float* __restrict__ b1, const float* __restrict__ b2,
    const float* __restrict__ b3, float* __restrict__ out)
{
    __shared__ __align__(16) char smem[SMEM_BYTES];
    ushort_t* v1hi  = (ushort_t*)(smem + 0);
    ushort_t* v1mid = (ushort_t*)(smem + 16384);
    ushort_t* v1lo  = (ushort_t*)(smem + 32768);
    ushort_t* A2    = (ushort_t*)(smem + 0);
    float*    xs    = (float*)(smem + 49152);
    ushort_t* v2B   = (ushort_t*)(smem + 50176);
    float*    Jsh   = (float*)(smem + 66560);
    float*    ydsh  = (float*)(smem + 69632);
    unsigned int* m1sh = (unsigned int*)(smem + 70016);

    const int tid  = threadIdx.x;
    const int lane = tid & 63;
    const int wave = tid >> 6;       // 0..7
    const int wg   = wave >> 2;      // group this wave serves in A2/cy/D phases
    const int w4   = wave & 3;       // role within group
    const int l15  = lane & 15;
    const int quad = lane >> 4;
    const int jz   = tid & 255;      // hidden unit for z1
    const int gz   = tid >> 8;       // sample group for z1

    // per-thread weight regs for z1 (thread jz == hidden unit)
    float w1r[8];
#pragma unroll
    for (int k = 0; k < 8; ++k) w1r[k] = w1[jz * 8 + k];
    const float b1r = b1[jz];
    float b2v[2];
#pragma unroll
    for (int n = 0; n < 2; ++n) b2v[n] = b2[(wave * 2 + n) * 16 + l15];

    const int g = blockIdx.x;
    const int s0 = g * 32;

    // ---- stage x for 32 samples ----
    if (tid < 256) {
        const int s = tid >> 3, k = tid & 7;
        float v;
        if (k < 6)       v = y[(s0 + s) * 6 + k];
        else if (k == 6) v = erate[s0 + s];
        else             v = Tin[s0 + s];
        xs[s * 8 + k] = v;
    }
    __syncthreads();  // (0)

    // ---- z1 (exact fp32) + 3-way bf16 split of v1 (A-frag, swizzled) + m1 mask -> LDS ----
    {
        unsigned int m1self = 0;  // bit s = (z1[gz*16+s][jz] > 0)
        const int ktw = jz >> 5, qd = (jz >> 3) & 3, jj = jz & 7;
        const int vb = gz * 4096;  // group region offset (ushorts)
#pragma unroll 4
        for (int s = 0; s < 16; ++s) {
            float z = b1r;
#pragma unroll
            for (int k = 0; k < 8; ++k) z = fmaf(w1r[k], xs[(gz * 16 + s) * 8 + k], z);
            const float v = fmaxf(z, 0.0f);
            m1self |= (v > 0.0f ? 1u : 0u) << s;
            const ushort_t hi = f2bf(v);
            const float r1 = v - bf2f(hi);
            const ushort_t mid = f2bf(r1);
            const int e = vb + swzu((ktw * 64 + (s | (qd << 4))) * 8 + jj);
            v1hi[e]  = hi;
            v1mid[e] = mid;
            v1lo[e]  = f2bf(r1 - bf2f(mid));
        }
        m1sh[tid] = m1self;  // [gz][jz]
    }
    __syncthreads();  // (1) splits + masks visible

    // ---- phase B: z2 = v1 @ w2^T, 3-way split (6 MFMAs), M=32 (2 groups) N=256 K=256 ----
    // Each wave: 2 n-tiles, both groups -> each B-fragment load feeds 2 MFMA sets.
    {
        f32x4 cz[2][2];  // [group][n]
#pragma unroll
        for (int gi = 0; gi < 2; ++gi)
#pragma unroll
            for (int n = 0; n < 2; ++n) cz[gi][n] = (f32x4){0, 0, 0, 0};
#pragma unroll 1
        for (int kt = 0; kt < 8; ++kt) {
            const int ao = swzo(kt * 64 + lane) * 8;
            bf16x8 ahi[2], ami[2], alo[2];
#pragma unroll
            for (int gi = 0; gi < 2; ++gi) {
                ahi[gi] = *(const bf16x8*)&v1hi[gi * 4096 + ao];
                ami[gi] = *(const bf16x8*)&v1mid[gi * 4096 + ao];
                alo[gi] = *(const bf16x8*)&v1lo[gi * 4096 + ao];
            }
#pragma unroll
            for (int n = 0; n < 2; ++n) {
                const int bidx = (((wave * 2 + n) * 8 + kt) * 64 + lane) * 8;
                bf16x8 bh = *(const bf16x8*)&g_w2T_hi[bidx];
                bf16x8 bm = *(const bf16x8*)&g_w2T_mid[bidx];
                bf16x8 bl = *(const bf16x8*)&g_w2T_lo[bidx];
                __builtin_amdgcn_s_setprio(1);
#pragma unroll
                for (int gi = 0; gi < 2; ++gi) {
                    cz[gi][n] = __builtin_amdgcn_mfma_f32_16x16x32_bf16(alo[gi], bh, cz[gi][n], 0, 0, 0);
                    cz[gi][n] = __builtin_amdgcn_mfma_f32_16x16x32_bf16(ami[gi], bm, cz[gi][n], 0, 0, 0);
                    cz[gi][n] = __builtin_amdgcn_mfma_f32_16x16x32_bf16(ahi[gi], bl, cz[gi][n], 0, 0, 0);
                    cz[gi][n] = __builtin_amdgcn_mfma_f32_16x16x32_bf16(ami[gi], bh, cz[gi][n], 0, 0, 0);
                    cz[gi][n] = __builtin_amdgcn_mfma_f32_16x16x32_bf16(ahi[gi], bm, cz[gi][n], 0, 0, 0);
                    cz[gi][n] = __builtin_amdgcn_mfma_f32_16x16x32_bf16(ahi[gi], bh, cz[gi][n], 0, 0, 0);
                }
                __builtin_amdgcn_s_setprio(0);
            }
        }
        // epilogue: v2 = relu(z2 + b2) -> v2B (B-frag layout, n=sample-in-group; = m2)
#pragma unroll
        for (int n = 0; n < 2; ++n) {
            const int h = (wave * 2 + n) * 16 + l15;
            const int ktd = h >> 5, qd = (h >> 3) & 3, jj = h & 7;
#pragma unroll
            for (int gi = 0; gi < 2; ++gi) {
#pragma unroll
                for (int r = 0; r < 4; ++r) {
                    const int s = quad * 4 + r;  // C layout: row = quad*4 + reg
                    const float v2 = fmaxf(cz[gi][n][r] + b2v[n], 0.0f);
                    v2B[gi * 4096 + swzu((ktd * 64 + (s | (qd << 4))) * 8 + jj)] = f2bf(v2);
                }
            }
        }
    }
    __syncthreads();  // (2) v2B visible; all v1 reads done -> A2 region writable

    // ---- chunks: per iteration, each group's chunk c handled in parallel ----
#pragma unroll 1
    for (int c = 0; c < 2; ++c) {
        // build A2[g][m = sl*6+i][h] = m2[g][sg][h] ? w3[i][h] : 0 (waves 0-2 g0, 4-6 g1)
        if (w4 < 3) {
            const int mt = w4;
            const int m = mt * 16 + l15;
            const int sl = m / 6, i = m - sl * 6;
            const int sg = c * 8 + sl;
#pragma unroll 1
            for (int kt = 0; kt < 8; ++kt) {
                bf16x8 vv = *(const bf16x8*)&v2B[wg * 4096 + swzo(kt * 64 + (sg | (quad << 4))) * 8];
                bf16x8 wv = *(const bf16x8*)&g_w3b[i * 256 + kt * 32 + quad * 8];
                bf16x8 o;
#pragma unroll
                for (int e = 0; e < 8; ++e)
                    o[e] = ((ushort_t)vv[e] != 0) ? wv[e] : (short)0;
                *(bf16x8*)&A2[wg * 12288 + swzo((mt * 8 + kt) * 64 + lane) * 8] = o;
            }
        }
        __syncthreads();  // (3) A2 visible

        // ydot tiles: wave 3 -> group 0, wave 7 -> group 1 (short; cy dies before cc loops)
        if (w4 == 3) {
            f32x4 cy[3];
#pragma unroll
            for (int mt = 0; mt < 3; ++mt) cy[mt] = (f32x4){0, 0, 0, 0};
#pragma unroll 1
            for (int kt = 0; kt < 8; ++kt) {
                bf16x8 bv = *(const bf16x8*)&v2B[wg * 4096 + swzo(kt * 64 + lane) * 8];
                __builtin_amdgcn_s_setprio(1);
#pragma unroll
                for (int mt = 0; mt < 3; ++mt) {
                    bf16x8 a = *(const bf16x8*)&A2[wg * 12288 + swzo((mt * 8 + kt) * 64 + lane) * 8];
                    cy[mt] = __builtin_amdgcn_mfma_f32_16x16x32_bf16(a, bv, cy[mt], 0, 0, 0);
                }
                __builtin_amdgcn_s_setprio(0);
            }
#pragma unroll
            for (int mt = 0; mt < 3; ++mt) {
#pragma unroll
                for (int r = 0; r < 4; ++r) {
                    const int m = mt * 16 + quad * 4 + r;
                    const int sl = m / 6, i = m - sl * 6;
                    if (l15 == c * 8 + sl) ydsh[wg * 48 + m] = cy[mt][r] + b3[i];
                }
            }
        }

        // phase C split by GROUP: pass gi computes B(gi) = A2[gi] @ w2 (M=48 N=256 K=256),
        // then (after the A2[gi]-read barrier) masks to Bm(gi) in place.
        // Live acc = 24 regs. Pass 2 re-reads the same b-frags (L2-hot).
#pragma unroll 1
        for (int gi = 0; gi < 2; ++gi) {
            f32x4 cc[3][2];  // [mt][n]
#pragma unroll
            for (int mt = 0; mt < 3; ++mt)
#pragma unroll
                for (int n = 0; n < 2; ++n) cc[mt][n] = (f32x4){0, 0, 0, 0};
#pragma unroll 1
            for (int kt = 0; kt < 8; ++kt) {
                bf16x8 a[3];
#pragma unroll
                for (int mt = 0; mt < 3; ++mt)
                    a[mt] = *(const bf16x8*)&A2[gi * 12288 + swzo((mt * 8 + kt) * 64 + lane) * 8];
#pragma unroll
                for (int n = 0; n < 2; ++n) {
                    bf16x8 b = *(const bf16x8*)&g_w2B[(((wave * 2 + n) * 8 + kt) * 64 + lane) * 8];
                    __builtin_amdgcn_s_setprio(1);
#pragma unroll
                    for (int mt = 0; mt < 3; ++mt)
                        cc[mt][n] = __builtin_amdgcn_mfma_f32_16x16x32_bf16(a[mt], b, cc[mt][n], 0, 0, 0);
                    __builtin_amdgcn_s_setprio(0);
                }
            }
            __syncthreads();  // (4.gi) all A2[gi] reads complete before Bm(gi) overwrites

            // Bm(gi) = (B .* m1) -> bf16 back into A2[gi]. Mask via m1sh (cross-wave).
#pragma unroll
            for (int n = 0; n < 2; ++n) {
                const int j = (wave * 2 + n) * 16 + l15;  // C layout: col = lane&15
                const unsigned int mcol = m1sh[gi * 256 + j];
                const int ktd = j >> 5, qd = (j >> 3) & 3, jjd = j & 7;
#pragma unroll
                for (int mt = 0; mt < 3; ++mt) {
#pragma unroll
                    for (int r = 0; r < 4; ++r) {
                        const int m = mt * 16 + quad * 4 + r;  // C layout: row = quad*4+reg
                        const int sg = c * 8 + m / 6;
                        const ushort_t bm =
                            ((mcol >> sg) & 1u) ? f2bf(cc[mt][n][r]) : (ushort_t)0;
                        A2[gi * 12288 + swzu(((mt * 8 + ktd) * 64 + ((m & 15) | (qd << 4))) * 8 + jjd)] = bm;
                    }
                }
            }
        }
        __syncthreads();  // (5) Bm both groups visible

        // phase D: J = Bm @ w1e, per group M=48 N=16 K=256; waves 0-2 (g0), 4-6 (g1)
        if (w4 < 3) {
            f32x4 dc = {0, 0, 0, 0};
#pragma unroll 1
            for (int kt = 0; kt < 8; ++kt) {
                bf16x8 a = *(const bf16x8*)&A2[wg * 12288 + swzo((w4 * 8 + kt) * 64 + lane) * 8];
                bf16x8 b = *(const bf16x8*)&g_w1e[(kt * 64 + lane) * 8];
                dc = __builtin_amdgcn_mfma_f32_16x16x32_bf16(a, b, dc, 0, 0, 0);
            }
            if (l15 < 8) {
#pragma unroll
                for (int r = 0; r < 4; ++r) {
                    const int m = w4 * 16 + quad * 4 + r;
                    Jsh[(wg * 48 + m) * 8 + l15] = dc[r];
                }
            }
        }
        __syncthreads();  // (6) Jsh/ydsh visible; all Bm reads done -> next chunk may overwrite

        // coalesced output: each group's 256 threads write that group's 8 samples
        {
            const int tg = tid & 255;
            const int s0c = s0 + gz * 16 + c * 8;
            const long base6 = (long)s0c * 6;
            {
                const int u = tg;  // dy dwords 0..255
                const int s = u / 36, rem = u - s * 36, ii = rem / 6, jy = rem - ii * 6;
                out[OFF_DY + (long)s0c * 36 + u] = Jsh[(gz * 48 + s * 6 + ii) * 8 + jy];
            }
            if (tg < 32) {  // dy dwords 256..287
                const int u = 256 + tg;
                const int s = u / 36, rem = u - s * 36, ii = rem / 6, jy = rem - ii * 6;
                out[OFF_DY + (long)s0c * 36 + u] = Jsh[(gz * 48 + s * 6 + ii) * 8 + jy];
            }
            if (tg < 48) out[OFF_YDOT + base6 + tg] = ydsh[gz * 48 + tg];
            const int t2 = tg - 64;
            if (t2 >= 0 && t2 < 48) out[OFF_DE + base6 + t2] = Jsh[(gz * 48 + t2) * 8 + 6];
            const int t3 = tg - 128;
            if (t3 >= 0 && t3 < 48) out[OFF_DT + base6 + t3] = Jsh[(gz * 48 + t3) * 8 + 7];
        }
    }
}

extern "C" void kernel_launch(void* const* d_in, const int* in_sizes, int n_in,
                              void* d_out, int out_size, void* d_ws, size_t ws_size,
                              hipStream_t stream) {
    // setup_inputs order: t(0,unused), y(1), erate(2), T(3), w1(4), w2(5), w3(6), b1(7), b2(8), b3(9)
    const float* y     = (const float*)d_in[1];
    const float* erate = (const float*)d_in[2];
    const float* Tin   = (const float*)d_in[3];
    const float* w1    = (const float*)d_in[4];
    const float* w2    = (const float*)d_in[5];
    const float* w3    = (const float*)d_in[6];
    const float* b1    = (const float*)d_in[7];
    const float* b2    = (const float*)d_in[8];
    const float* b3    = (const float*)d_in[9];
    float* out = (float*)d_out;

    prep_kernel<<<dim3(64), dim3(256), 0, stream>>>(w1, w2, w3);
    fused_kernel<<<dim3(NG32), dim3(512), 0, stream>>>(
        y, erate, Tin, w1, b1, b2, b3, out);
}

// Round 12
// 229.788 us; speedup vs baseline: 1.6440x; 1.0265x over previous
//
#include <hip/hip_runtime.h>
#include <hip/hip_bf16.h>

// NeuralInelasticModel fused fwd + Jacobian, MFMA bf16.
// V16 = V15 + packed A2-build mask in C ext-vector form (R9's bit-trick done right:
//   the compiler replicates VOP3P constants to both 16-bit halves; hand asm did not).
//   m = (short8)(v + 0x7fff) >> 15; o = w & m.  relu-bf16 has sign bit 0, so
//   v==0 -> 0x7FFF -> mask 0; v>=1 -> >=0x8000 -> mask 0xFFFF. Bit-identical select.
// V15 ledger (R11): WRITE 93->62MB (residual spill ~11 dw/thread), dur 190us ~= V13's 187
//   (spill gain cancelled by unroll-1 ILP loss). Spill lever exhausted: demand ~139 vs
//   cap 128 (waves/SIMD x (arch+acc) <= 512; reported VGPR_Count excludes acc).
// Remaining pipes: VALU 41% (widest), MFMA 25% (~47us, near the ~45us floor -- the
//   3-way z2 split is numerically required for m2 mask sign), HBM 4.6%.
// Carried: 32 samples/block, 512 thr, 2 blk/CU; XOR bank-swizzle; s_setprio on MFMA;
//   cy hoist; LDS m1 masks; phase C split by group; unroll-1 loops.

typedef unsigned short ushort_t;
typedef __attribute__((ext_vector_type(8))) short bf16x8;   // 8 bf16 = 4 VGPRs
typedef __attribute__((ext_vector_type(8))) unsigned short u16x8;
typedef __attribute__((ext_vector_type(4))) float f32x4;

#define NSAMP (64 * 1024)
#define NG32 (NSAMP / 32)
#define OFF_YDOT 0
#define OFF_DY (NSAMP * 6)
#define OFF_DE (OFF_DY + NSAMP * 36)
#define OFF_DT (OFF_DE + NSAMP * 6)

// Weights repacked into MFMA B-fragment order:
// frag elem idx = ((nt*8 + kt)*64 + lane)*8 + jj,
// value = B[k = kt*32 + (lane>>4)*8 + jj][n = nt*16 + (lane&15)]
__device__ __align__(16) ushort_t g_w2T_hi[65536];   // z2 GEMM: B[k=j][n=h] = w2[h][j]
__device__ __align__(16) ushort_t g_w2T_mid[65536];
__device__ __align__(16) ushort_t g_w2T_lo[65536];
__device__ __align__(16) ushort_t g_w2B[65536];      // B GEMM:  B[k=h][n=j] = w2[h][j]
__device__ __align__(16) ushort_t g_w1e[4096];       // J GEMM:  B[k=j][n=kout] = w1[j][kout] (kout<8 else 0)
__device__ __align__(16) ushort_t g_w3b[1536];       // w3 bf16 row-major [6][256]

static __device__ __forceinline__ ushort_t f2bf(float f) {
    union { __hip_bfloat16 b; ushort_t u; } c;
    c.b = __float2bfloat16(f);
    return c.u;
}
static __device__ __forceinline__ float bf2f(ushort_t u) {
    union { ushort_t u; __hip_bfloat16 b; } c;
    c.u = u;
    return __bfloat162float(c.b);
}

// Bank swizzle for bf16 frag regions (region bases 1KiB-aligned):
// fold byte-addr bits [9:8] into bank bits [6:5]. Involution; 16B-block-preserving.
static __device__ __forceinline__ int swzu(int E) { return E ^ ((E >> 3) & 0x30); }  // ushort idx
static __device__ __forceinline__ int swzo(int o) { return o ^ ((o >> 3) & 0x6); }   // 16B-octet idx

__global__ void prep_kernel(const float* __restrict__ w1, const float* __restrict__ w2,
                            const float* __restrict__ w3) {
    const int gtid = blockIdx.x * blockDim.x + threadIdx.x;
    const int stride = gridDim.x * blockDim.x;
    for (int idx = gtid; idx < 65536; idx += stride) {
        const int nt = idx >> 12, kt = (idx >> 9) & 7, L = (idx >> 3) & 63, jj = idx & 7;
        const int n = nt * 16 + (L & 15);
        const int k = kt * 32 + ((L >> 4) & 3) * 8 + jj;
        const float vT = w2[n * 256 + k];          // w2T: B[k=j][n=h]
        const ushort_t hi = f2bf(vT);
        const float r1 = vT - bf2f(hi);
        const ushort_t mid = f2bf(r1);
        g_w2T_hi[idx]  = hi;
        g_w2T_mid[idx] = mid;
        g_w2T_lo[idx]  = f2bf(r1 - bf2f(mid));
        g_w2B[idx] = f2bf(w2[k * 256 + n]);        // w2B: B[k=h][n=j]
    }
    for (int idx = gtid; idx < 4096; idx += stride) {
        const int kt = idx >> 9, L = (idx >> 3) & 63, jj = idx & 7;
        const int kout = L & 15;
        const int j = kt * 32 + ((L >> 4) & 3) * 8 + jj;
        g_w1e[idx] = (kout < 8) ? f2bf(w1[j * 8 + kout]) : (ushort_t)0;
    }
    for (int idx = gtid; idx < 1536; idx += stride) g_w3b[idx] = f2bf(w3[idx]);
}

// LDS layout (72064 B -> 2 blocks/CU), bf16 frag regions XOR-swizzled, 1KB-aligned bases:
//   [0, 49152)     v1hi [2g][4096 u16] @0 | v1mid @16384 | v1lo @32768. Dead after B.
//                    Post-B alias: A2/Bm [2 g][3 mt][8 kt][64][8] bf16 (2 x 24576 B).
//   [49152, 50176) xs: 32 samples x 8 f32.
//   [50176, 66560) v2B [2 g][8 kt][64][8] bf16; n-dim = sample-in-group; = m2 mask.
//   [66560, 69632) Jsh [2 g][48][8] f32.
//   [69632, 70016) ydsh [2 g][48] f32.
//   [70016, 72064) m1sh [2 g][256] u32 (z1 masks, bit s = sample-in-group).
#define SMEM_BYTES 72064

__global__ __launch_bounds__(512, 4) void fused_kernel(
    const float* __restrict__ y, const float* __restrict__ erate,
    const float* __restrict__ Tin, const float* __restrict__ w1,
    const float* __restrict__ b1, const float* __restrict__ b2,
    const float* __restrict__ b3, float* __restrict__ out)
{
    __shared__ __align__(16) char smem[SMEM_BYTES];
    ushort_t* v1hi  = (ushort_t*)(smem + 0);
    ushort_t* v1mid = (ushort_t*)(smem + 16384);
    ushort_t* v1lo  = (ushort_t*)(smem + 32768);
    ushort_t* A2    = (ushort_t*)(smem + 0);
    float*    xs    = (float*)(smem + 49152);
    ushort_t* v2B   = (ushort_t*)(smem + 50176);
    float*    Jsh   = (float*)(smem + 66560);
    float*    ydsh  = (float*)(smem + 69632);
    unsigned int* m1sh = (unsigned int*)(smem + 70016);

    const int tid  = threadIdx.x;
    const int lane = tid & 63;
    const int wave = tid >> 6;       // 0..7
    const int wg   = wave >> 2;      // group this wave serves in A2/cy/D phases
    const int w4   = wave & 3;       // role within group
    const int l15  = lane & 15;
    const int quad = lane >> 4;
    const int jz   = tid & 255;      // hidden unit for z1
    const int gz   = tid >> 8;       // sample group for z1

    // per-thread weight regs for z1 (thread jz == hidden unit)
    float w1r[8];
#pragma unroll
    for (int k = 0; k < 8; ++k) w1r[k] = w1[jz * 8 + k];
    const float b1r = b1[jz];
    float b2v[2];
#pragma unroll
    for (int n = 0; n < 2; ++n) b2v[n] = b2[(wave * 2 + n) * 16 + l15];

    const int g = blockIdx.x;
    const int s0 = g * 32;

    // ---- stage x for 32 samples ----
    if (tid < 256) {
        const int s = tid >> 3, k = tid & 7;
        float v;
        if (k < 6)       v = y[(s0 + s) * 6 + k];
        else if (k == 6) v = erate[s0 + s];
        else             v = Tin[s0 + s];
        xs[s * 8 + k] = v;
    }
    __syncthreads();  // (0)

    // ---- z1 (exact fp32) + 3-way bf16 split of v1 (A-frag, swizzled) + m1 mask -> LDS ----
    {
        unsigned int m1self = 0;  // bit s = (z1[gz*16+s][jz] > 0)
        const int ktw = jz >> 5, qd = (jz >> 3) & 3, jj = jz & 7;
        const int vb = gz * 4096;  // group region offset (ushorts)
#pragma unroll 4
        for (int s = 0; s < 16; ++s) {
            float z = b1r;
#pragma unroll
            for (int k = 0; k < 8; ++k) z = fmaf(w1r[k], xs[(gz * 16 + s) * 8 + k], z);
            const float v = fmaxf(z, 0.0f);
            m1self |= (v > 0.0f ? 1u : 0u) << s;
            const ushort_t hi = f2bf(v);
            const float r1 = v - bf2f(hi);
            const ushort_t mid = f2bf(r1);
            const int e = vb + swzu((ktw * 64 + (s | (qd << 4))) * 8 + jj);
            v1hi[e]  = hi;
            v1mid[e] = mid;
            v1lo[e]  = f2bf(r1 - bf2f(mid));
        }
        m1sh[tid] = m1self;  // [gz][jz]
    }
    __syncthreads();  // (1) splits + masks visible

    // ---- phase B: z2 = v1 @ w2^T, 3-way split (6 MFMAs), M=32 (2 groups) N=256 K=256 ----
    // Each wave: 2 n-tiles, both groups -> each B-fragment load feeds 2 MFMA sets.
    {
        f32x4 cz[2][2];  // [group][n]
#pragma unroll
        for (int gi = 0; gi < 2; ++gi)
#pragma unroll
            for (int n = 0; n < 2; ++n) cz[gi][n] = (f32x4){0, 0, 0, 0};
#pragma unroll 1
        for (int kt = 0; kt < 8; ++kt) {
            const int ao = swzo(kt * 64 + lane) * 8;
            bf16x8 ahi[2], ami[2], alo[2];
#pragma unroll
            for (int gi = 0; gi < 2; ++gi) {
                ahi[gi] = *(const bf16x8*)&v1hi[gi * 4096 + ao];
                ami[gi] = *(const bf16x8*)&v1mid[gi * 4096 + ao];
                alo[gi] = *(const bf16x8*)&v1lo[gi * 4096 + ao];
            }
#pragma unroll
            for (int n = 0; n < 2; ++n) {
                const int bidx = (((wave * 2 + n) * 8 + kt) * 64 + lane) * 8;
                bf16x8 bh = *(const bf16x8*)&g_w2T_hi[bidx];
                bf16x8 bm = *(const bf16x8*)&g_w2T_mid[bidx];
                bf16x8 bl = *(const bf16x8*)&g_w2T_lo[bidx];
                __builtin_amdgcn_s_setprio(1);
#pragma unroll
                for (int gi = 0; gi < 2; ++gi) {
                    cz[gi][n] = __builtin_amdgcn_mfma_f32_16x16x32_bf16(alo[gi], bh, cz[gi][n], 0, 0, 0);
                    cz[gi][n] = __builtin_amdgcn_mfma_f32_16x16x32_bf16(ami[gi], bm, cz[gi][n], 0, 0, 0);
                    cz[gi][n] = __builtin_amdgcn_mfma_f32_16x16x32_bf16(ahi[gi], bl, cz[gi][n], 0, 0, 0);
                    cz[gi][n] = __builtin_amdgcn_mfma_f32_16x16x32_bf16(ami[gi], bh, cz[gi][n], 0, 0, 0);
                    cz[gi][n] = __builtin_amdgcn_mfma_f32_16x16x32_bf16(ahi[gi], bm, cz[gi][n], 0, 0, 0);
                    cz[gi][n] = __builtin_amdgcn_mfma_f32_16x16x32_bf16(ahi[gi], bh, cz[gi][n], 0, 0, 0);
                }
                __builtin_amdgcn_s_setprio(0);
            }
        }
        // epilogue: v2 = relu(z2 + b2) -> v2B (B-frag layout, n=sample-in-group; = m2)
#pragma unroll
        for (int n = 0; n < 2; ++n) {
            const int h = (wave * 2 + n) * 16 + l15;
            const int ktd = h >> 5, qd = (h >> 3) & 3, jj = h & 7;
#pragma unroll
            for (int gi = 0; gi < 2; ++gi) {
#pragma unroll
                for (int r = 0; r < 4; ++r) {
                    const int s = quad * 4 + r;  // C layout: row = quad*4 + reg
                    const float v2 = fmaxf(cz[gi][n][r] + b2v[n], 0.0f);
                    v2B[gi * 4096 + swzu((ktd * 64 + (s | (qd << 4))) * 8 + jj)] = f2bf(v2);
                }
            }
        }
    }
    __syncthreads();  // (2) v2B visible; all v1 reads done -> A2 region writable

    // ---- chunks: per iteration, each group's chunk c handled in parallel ----
#pragma unroll 1
    for (int c = 0; c < 2; ++c) {
        // build A2[g][m = sl*6+i][h] = m2[g][sg][h] ? w3[i][h] : 0 (waves 0-2 g0, 4-6 g1)
        // Packed C ext-vector bit-trick (bit-identical to the ternary select):
        //   relu-bf16 v has sign bit 0 -> v in [0,0x7F80]; (v+0x7fff) has bit15 set iff v!=0.
        //   mask = arithmetic >>15 of that (0 or 0xFFFF per element); o = w & mask.
        if (w4 < 3) {
            const int mt = w4;
            const int m = mt * 16 + l15;
            const int sl = m / 6, i = m - sl * 6;
            const int sg = c * 8 + sl;
#pragma unroll 1
            for (int kt = 0; kt < 8; ++kt) {
                u16x8 vv = *(const u16x8*)&v2B[wg * 4096 + swzo(kt * 64 + (sg | (quad << 4))) * 8];
                bf16x8 wv = *(const bf16x8*)&g_w3b[i * 256 + kt * 32 + quad * 8];
                bf16x8 t = (bf16x8)(vv + (unsigned short)0x7fffu);  // v_pk_add_u16 (wraps)
                bf16x8 msk = t >> 15;                               // arith shift: 0 / 0xFFFF
                bf16x8 o = wv & msk;
                *(bf16x8*)&A2[wg * 12288 + swzo((mt * 8 + kt) * 64 + lane) * 8] = o;
            }
        }
        __syncthreads();  // (3) A2 visible

        // ydot tiles: wave 3 -> group 0, wave 7 -> group 1 (short; cy dies before cc loops)
        if (w4 == 3) {
            f32x4 cy[3];
#pragma unroll
            for (int mt = 0; mt < 3; ++mt) cy[mt] = (f32x4){0, 0, 0, 0};
#pragma unroll 1
            for (int kt = 0; kt < 8; ++kt) {
                bf16x8 bv = *(const bf16x8*)&v2B[wg * 4096 + swzo(kt * 64 + lane) * 8];
                __builtin_amdgcn_s_setprio(1);
#pragma unroll
                for (int mt = 0; mt < 3; ++mt) {
                    bf16x8 a = *(const bf16x8*)&A2[wg * 12288 + swzo((mt * 8 + kt) * 64 + lane) * 8];
                    cy[mt] = __builtin_amdgcn_mfma_f32_16x16x32_bf16(a, bv, cy[mt], 0, 0, 0);
                }
                __builtin_amdgcn_s_setprio(0);
            }
#pragma unroll
            for (int mt = 0; mt < 3; ++mt) {
#pragma unroll
                for (int r = 0; r < 4; ++r) {
                    const int m = mt * 16 + quad * 4 + r;
                    const int sl = m / 6, i = m - sl * 6;
                    if (l15 == c * 8 + sl) ydsh[wg * 48 + m] = cy[mt][r] + b3[i];
                }
            }
        }

        // phase C split by GROUP: pass gi computes B(gi) = A2[gi] @ w2 (M=48 N=256 K=256),
        // then (after the A2[gi]-read barrier) masks to Bm(gi) in place.
        // Live acc = 24 regs. Pass 2 re-reads the same b-frags (L2-hot).
#pragma unroll 1
        for (int gi = 0; gi < 2; ++gi) {
            f32x4 cc[3][2];  // [mt][n]
#pragma unroll
            for (int mt = 0; mt < 3; ++mt)
#pragma unroll
                for (int n = 0; n < 2; ++n) cc[mt][n] = (f32x4){0, 0, 0, 0};
#pragma unroll 1
            for (int kt = 0; kt < 8; ++kt) {
                bf16x8 a[3];
#pragma unroll
                for (int mt = 0; mt < 3; ++mt)
                    a[mt] = *(const bf16x8*)&A2[gi * 12288 + swzo((mt * 8 + kt) * 64 + lane) * 8];
#pragma unroll
                for (int n = 0; n < 2; ++n) {
                    bf16x8 b = *(const bf16x8*)&g_w2B[(((wave * 2 + n) * 8 + kt) * 64 + lane) * 8];
                    __builtin_amdgcn_s_setprio(1);
#pragma unroll
                    for (int mt = 0; mt < 3; ++mt)
                        cc[mt][n] = __builtin_amdgcn_mfma_f32_16x16x32_bf16(a[mt], b, cc[mt][n], 0, 0, 0);
                    __builtin_amdgcn_s_setprio(0);
                }
            }
            __syncthreads();  // (4.gi) all A2[gi] reads complete before Bm(gi) overwrites

            // Bm(gi) = (B .* m1) -> bf16 back into A2[gi]. Mask via m1sh (cross-wave).
#pragma unroll
            for (int n = 0; n < 2; ++n) {
                const int j = (wave * 2 + n) * 16 + l15;  // C layout: col = lane&15
                const unsigned int mcol = m1sh[gi * 256 + j];
                const int ktd = j >> 5, qd = (j >> 3) & 3, jjd = j & 7;
#pragma unroll
                for (int mt = 0; mt < 3; ++mt) {
#pragma unroll
                    for (int r = 0; r < 4; ++r) {
                        const int m = mt * 16 + quad * 4 + r;  // C layout: row = quad*4+reg
                        const int sg = c * 8 + m / 6;
                        const ushort_t bm =
                            ((mcol >> sg) & 1u) ? f2bf(cc[mt][n][r]) : (ushort_t)0;
                        A2[gi * 12288 + swzu(((mt * 8 + ktd) * 64 + ((m & 15) | (qd << 4))) * 8 + jjd)] = bm;
                    }
                }
            }
        }
        __syncthreads();  // (5) Bm both groups visible

        // phase D: J = Bm @ w1e, per group M=48 N=16 K=256; waves 0-2 (g0), 4-6 (g1)
        if (w4 < 3) {
            f32x4 dc = {0, 0, 0, 0};
#pragma unroll 1
            for (int kt = 0; kt < 8; ++kt) {
                bf16x8 a = *(const bf16x8*)&A2[wg * 12288 + swzo((w4 * 8 + kt) * 64 + lane) * 8];
                bf16x8 b = *(const bf16x8*)&g_w1e[(kt * 64 + lane) * 8];
                dc = __builtin_amdgcn_mfma_f32_16x16x32_bf16(a, b, dc, 0, 0, 0);
            }
            if (l15 < 8) {
#pragma unroll
                for (int r = 0; r < 4; ++r) {
                    const int m = w4 * 16 + quad * 4 + r;
                    Jsh[(wg * 48 + m) * 8 + l15] = dc[r];
                }
            }
        }
        __syncthreads();  // (6) Jsh/ydsh visible; all Bm reads done -> next chunk may overwrite

        // coalesced output: each group's 256 threads write that group's 8 samples
        {
            const int tg = tid & 255;
            const int s0c = s0 + gz * 16 + c * 8;
            const long base6 = (long)s0c * 6;
            {
                const int u = tg;  // dy dwords 0..255
                const int s = u / 36, rem = u - s * 36, ii = rem / 6, jy = rem - ii * 6;
                out[OFF_DY + (long)s0c * 36 + u] = Jsh[(gz * 48 + s * 6 + ii) * 8 + jy];
            }
            if (tg < 32) {  // dy dwords 256..287
                const int u = 256 + tg;
                const int s = u / 36, rem = u - s * 36, ii = rem / 6, jy = rem - ii * 6;
                out[OFF_DY + (long)s0c * 36 + u] = Jsh[(gz * 48 + s * 6 + ii) * 8 + jy];
            }
            if (tg < 48) out[OFF_YDOT + base6 + tg] = ydsh[gz * 48 + tg];
            const int t2 = tg - 64;
            if (t2 >= 0 && t2 < 48) out[OFF_DE + base6 + t2] = Jsh[(gz * 48 + t2) * 8 + 6];
            const int t3 = tg - 128;
            if (t3 >= 0 && t3 < 48) out[OFF_DT + base6 + t3] = Jsh[(gz * 48 + t3) * 8 + 7];
        }
    }
}

extern "C" void kernel_launch(void* const* d_in, const int* in_sizes, int n_in,
                              void* d_out, int out_size, void* d_ws, size_t ws_size,
                              hipStream_t stream) {
    // setup_inputs order: t(0,unused), y(1), erate(2), T(3), w1(4), w2(5), w3(6), b1(7), b2(8), b3(9)
    const float* y     = (const float*)d_in[1];
    const float* erate = (const float*)d_in[2];
    const float* Tin   = (const float*)d_in[3];
    const float* w1    = (const float*)d_in[4];
    const float* w2    = (const float*)d_in[5];
    const float* w3    = (const float*)d_in[6];
    const float* b1    = (const float*)d_in[7];
    const float* b2    = (const float*)d_in[8];
    const float* b3    = (const float*)d_in[9];
    float* out = (float*)d_out;

    prep_kernel<<<dim3(64), dim3(256), 0, stream>>>(w1, w2, w3);
    fused_kernel<<<dim3(NG32), dim3(512), 0, stream>>>(
        y, erate, Tin, w1, b1, b2, b3, out);
}

// Round 13
// 225.783 us; speedup vs baseline: 1.6732x; 1.0177x over previous
//
#include <hip/hip_runtime.h>
#include <hip/hip_bf16.h>

// NeuralInelasticModel fused fwd + Jacobian, MFMA bf16.
// V17 = V16 + packed PAIR conversions in both f32->bf16 epilogues:
//   - Bm writeback: __float22bfloat162_rn (1x v_cvt_pk_bf16_f32 per 2 elems, RNE ==
//     __float2bfloat16) + 32-bit AND mask for the m1 select (R12's proven trick class).
//   - v2B epilogue: same pairing for relu(z2+b2) conversion.
//   Stores remain scalar ds_write_b16 (pair elems are 16B apart in frag layout).
// V16 ledger (R12): 180.6us, MfmaUtil 26.5 (~48us, near the ~45us MFMA floor),
//   VALU 40.7 (~73us, widest pipe), HBM 4.9%, WRITE 62MB residual spill (lever
//   exhausted: R11 showed reg<->ILP now zero-sum at the 128-reg cap).
// Carried: 32 samp/block, 512 thr, 2 blk/CU; XOR bank-swizzle; s_setprio on MFMA;
//   cy hoist; LDS m1 masks; phase C split by group; unroll-1 loops; packed A2 mask.
// R9 lesson (enforced): packed 16-bit tricks in C ext-vector/intrinsic form ONLY --
//   hand VOP3P asm does not replicate inline constants to both halves.

typedef unsigned short ushort_t;
typedef __attribute__((ext_vector_type(8))) short bf16x8;   // 8 bf16 = 4 VGPRs
typedef __attribute__((ext_vector_type(8))) unsigned short u16x8;
typedef __attribute__((ext_vector_type(4))) float f32x4;

#define NSAMP (64 * 1024)
#define NG32 (NSAMP / 32)
#define OFF_YDOT 0
#define OFF_DY (NSAMP * 6)
#define OFF_DE (OFF_DY + NSAMP * 36)
#define OFF_DT (OFF_DE + NSAMP * 6)

// Weights repacked into MFMA B-fragment order:
// frag elem idx = ((nt*8 + kt)*64 + lane)*8 + jj,
// value = B[k = kt*32 + (lane>>4)*8 + jj][n = nt*16 + (lane&15)]
__device__ __align__(16) ushort_t g_w2T_hi[65536];   // z2 GEMM: B[k=j][n=h] = w2[h][j]
__device__ __align__(16) ushort_t g_w2T_mid[65536];
__device__ __align__(16) ushort_t g_w2T_lo[65536];
__device__ __align__(16) ushort_t g_w2B[65536];      // B GEMM:  B[k=h][n=j] = w2[h][j]
__device__ __align__(16) ushort_t g_w1e[4096];       // J GEMM:  B[k=j][n=kout] = w1[j][kout] (kout<8 else 0)
__device__ __align__(16) ushort_t g_w3b[1536];       // w3 bf16 row-major [6][256]

static __device__ __forceinline__ ushort_t f2bf(float f) {
    union { __hip_bfloat16 b; ushort_t u; } c;
    c.b = __float2bfloat16(f);
    return c.u;
}
static __device__ __forceinline__ float bf2f(ushort_t u) {
    union { ushort_t u; __hip_bfloat16 b; } c;
    c.u = u;
    return __bfloat162float(c.b);
}
// packed pair f32->bf16 (RNE, bit-identical to f2bf per element): returns lo|hi<<16
static __device__ __forceinline__ unsigned int f2bf_pk(float a0, float a1) {
    union { __hip_bfloat162 b; unsigned int u; } c;
    c.b = __float22bfloat162_rn(float2{a0, a1});
    return c.u;
}

// Bank swizzle for bf16 frag regions (region bases 1KiB-aligned):
// fold byte-addr bits [9:8] into bank bits [6:5]. Involution; 16B-block-preserving.
static __device__ __forceinline__ int swzu(int E) { return E ^ ((E >> 3) & 0x30); }  // ushort idx
static __device__ __forceinline__ int swzo(int o) { return o ^ ((o >> 3) & 0x6); }   // 16B-octet idx

__global__ void prep_kernel(const float* __restrict__ w1, const float* __restrict__ w2,
                            const float* __restrict__ w3) {
    const int gtid = blockIdx.x * blockDim.x + threadIdx.x;
    const int stride = gridDim.x * blockDim.x;
    for (int idx = gtid; idx < 65536; idx += stride) {
        const int nt = idx >> 12, kt = (idx >> 9) & 7, L = (idx >> 3) & 63, jj = idx & 7;
        const int n = nt * 16 + (L & 15);
        const int k = kt * 32 + ((L >> 4) & 3) * 8 + jj;
        const float vT = w2[n * 256 + k];          // w2T: B[k=j][n=h]
        const ushort_t hi = f2bf(vT);
        const float r1 = vT - bf2f(hi);
        const ushort_t mid = f2bf(r1);
        g_w2T_hi[idx]  = hi;
        g_w2T_mid[idx] = mid;
        g_w2T_lo[idx]  = f2bf(r1 - bf2f(mid));
        g_w2B[idx] = f2bf(w2[k * 256 + n]);        // w2B: B[k=h][n=j]
    }
    for (int idx = gtid; idx < 4096; idx += stride) {
        const int kt = idx >> 9, L = (idx >> 3) & 63, jj = idx & 7;
        const int kout = L & 15;
        const int j = kt * 32 + ((L >> 4) & 3) * 8 + jj;
        g_w1e[idx] = (kout < 8) ? f2bf(w1[j * 8 + kout]) : (ushort_t)0;
    }
    for (int idx = gtid; idx < 1536; idx += stride) g_w3b[idx] = f2bf(w3[idx]);
}

// LDS layout (72064 B -> 2 blocks/CU), bf16 frag regions XOR-swizzled, 1KB-aligned bases:
//   [0, 49152)     v1hi [2g][4096 u16] @0 | v1mid @16384 | v1lo @32768. Dead after B.
//                    Post-B alias: A2/Bm [2 g][3 mt][8 kt][64][8] bf16 (2 x 24576 B).
//   [49152, 50176) xs: 32 samples x 8 f32.
//   [50176, 66560) v2B [2 g][8 kt][64][8] bf16; n-dim = sample-in-group; = m2 mask.
//   [66560, 69632) Jsh [2 g][48][8] f32.
//   [69632, 70016) ydsh [2 g][48] f32.
//   [70016, 72064) m1sh [2 g][256] u32 (z1 masks, bit s = sample-in-group).
#define SMEM_BYTES 72064

__global__ __launch_bounds__(512, 4) void fused_kernel(
    const float* __restrict__ y, const float* __restrict__ erate,
    const float* __restrict__ Tin, const float* __restrict__ w1,
    const float* __restrict__ b1, const float* __restrict__ b2,
    const float* __restrict__ b3, float* __restrict__ out)
{
    __shared__ __align__(16) char smem[SMEM_BYTES];
    ushort_t* v1hi  = (ushort_t*)(smem + 0);
    ushort_t* v1mid = (ushort_t*)(smem + 16384);
    ushort_t* v1lo  = (ushort_t*)(smem + 32768);
    ushort_t* A2    = (ushort_t*)(smem + 0);
    float*    xs    = (float*)(smem + 49152);
    ushort_t* v2B   = (ushort_t*)(smem + 50176);
    float*    Jsh   = (float*)(smem + 66560);
    float*    ydsh  = (float*)(smem + 69632);
    unsigned int* m1sh = (unsigned int*)(smem + 70016);

    const int tid  = threadIdx.x;
    const int lane = tid & 63;
    const int wave = tid >> 6;       // 0..7
    const int wg   = wave >> 2;      // group this wave serves in A2/cy/D phases
    const int w4   = wave & 3;       // role within group
    const int l15  = lane & 15;
    const int quad = lane >> 4;
    const int jz   = tid & 255;      // hidden unit for z1
    const int gz   = tid >> 8;       // sample group for z1

    // per-thread weight regs for z1 (thread jz == hidden unit)
    float w1r[8];
#pragma unroll
    for (int k = 0; k < 8; ++k) w1r[k] = w1[jz * 8 + k];
    const float b1r = b1[jz];
    float b2v[2];
#pragma unroll
    for (int n = 0; n < 2; ++n) b2v[n] = b2[(wave * 2 + n) * 16 + l15];

    const int g = blockIdx.x;
    const int s0 = g * 32;

    // ---- stage x for 32 samples ----
    if (tid < 256) {
        const int s = tid >> 3, k = tid & 7;
        float v;
        if (k < 6)       v = y[(s0 + s) * 6 + k];
        else if (k == 6) v = erate[s0 + s];
        else             v = Tin[s0 + s];
        xs[s * 8 + k] = v;
    }
    __syncthreads();  // (0)

    // ---- z1 (exact fp32) + 3-way bf16 split of v1 (A-frag, swizzled) + m1 mask -> LDS ----
    {
        unsigned int m1self = 0;  // bit s = (z1[gz*16+s][jz] > 0)
        const int ktw = jz >> 5, qd = (jz >> 3) & 3, jj = jz & 7;
        const int vb = gz * 4096;  // group region offset (ushorts)
#pragma unroll 4
        for (int s = 0; s < 16; ++s) {
            float z = b1r;
#pragma unroll
            for (int k = 0; k < 8; ++k) z = fmaf(w1r[k], xs[(gz * 16 + s) * 8 + k], z);
            const float v = fmaxf(z, 0.0f);
            m1self |= (v > 0.0f ? 1u : 0u) << s;
            const ushort_t hi = f2bf(v);
            const float r1 = v - bf2f(hi);
            const ushort_t mid = f2bf(r1);
            const int e = vb + swzu((ktw * 64 + (s | (qd << 4))) * 8 + jj);
            v1hi[e]  = hi;
            v1mid[e] = mid;
            v1lo[e]  = f2bf(r1 - bf2f(mid));
        }
        m1sh[tid] = m1self;  // [gz][jz]
    }
    __syncthreads();  // (1) splits + masks visible

    // ---- phase B: z2 = v1 @ w2^T, 3-way split (6 MFMAs), M=32 (2 groups) N=256 K=256 ----
    // Each wave: 2 n-tiles, both groups -> each B-fragment load feeds 2 MFMA sets.
    {
        f32x4 cz[2][2];  // [group][n]
#pragma unroll
        for (int gi = 0; gi < 2; ++gi)
#pragma unroll
            for (int n = 0; n < 2; ++n) cz[gi][n] = (f32x4){0, 0, 0, 0};
#pragma unroll 1
        for (int kt = 0; kt < 8; ++kt) {
            const int ao = swzo(kt * 64 + lane) * 8;
            bf16x8 ahi[2], ami[2], alo[2];
#pragma unroll
            for (int gi = 0; gi < 2; ++gi) {
                ahi[gi] = *(const bf16x8*)&v1hi[gi * 4096 + ao];
                ami[gi] = *(const bf16x8*)&v1mid[gi * 4096 + ao];
                alo[gi] = *(const bf16x8*)&v1lo[gi * 4096 + ao];
            }
#pragma unroll
            for (int n = 0; n < 2; ++n) {
                const int bidx = (((wave * 2 + n) * 8 + kt) * 64 + lane) * 8;
                bf16x8 bh = *(const bf16x8*)&g_w2T_hi[bidx];
                bf16x8 bm = *(const bf16x8*)&g_w2T_mid[bidx];
                bf16x8 bl = *(const bf16x8*)&g_w2T_lo[bidx];
                __builtin_amdgcn_s_setprio(1);
#pragma unroll
                for (int gi = 0; gi < 2; ++gi) {
                    cz[gi][n] = __builtin_amdgcn_mfma_f32_16x16x32_bf16(alo[gi], bh, cz[gi][n], 0, 0, 0);
                    cz[gi][n] = __builtin_amdgcn_mfma_f32_16x16x32_bf16(ami[gi], bm, cz[gi][n], 0, 0, 0);
                    cz[gi][n] = __builtin_amdgcn_mfma_f32_16x16x32_bf16(ahi[gi], bl, cz[gi][n], 0, 0, 0);
                    cz[gi][n] = __builtin_amdgcn_mfma_f32_16x16x32_bf16(ami[gi], bh, cz[gi][n], 0, 0, 0);
                    cz[gi][n] = __builtin_amdgcn_mfma_f32_16x16x32_bf16(ahi[gi], bm, cz[gi][n], 0, 0, 0);
                    cz[gi][n] = __builtin_amdgcn_mfma_f32_16x16x32_bf16(ahi[gi], bh, cz[gi][n], 0, 0, 0);
                }
                __builtin_amdgcn_s_setprio(0);
            }
        }
        // epilogue: v2 = relu(z2 + b2) -> v2B (B-frag, n=sample-in-group; = m2).
        // Packed pair conversion: 1 cvt_pk per 2 rows (RNE == per-element f2bf).
#pragma unroll
        for (int n = 0; n < 2; ++n) {
            const int h = (wave * 2 + n) * 16 + l15;
            const int ktd = h >> 5, qd = (h >> 3) & 3, jj = h & 7;
#pragma unroll
            for (int gi = 0; gi < 2; ++gi) {
#pragma unroll
                for (int rp = 0; rp < 2; ++rp) {
                    const float a0 = fmaxf(cz[gi][n][2 * rp] + b2v[n], 0.0f);
                    const float a1 = fmaxf(cz[gi][n][2 * rp + 1] + b2v[n], 0.0f);
                    const unsigned int pk = f2bf_pk(a0, a1);
                    const int se = quad * 4 + 2 * rp;  // C layout: row = quad*4 + reg
                    v2B[gi * 4096 + swzu((ktd * 64 + (se | (qd << 4))) * 8 + jj)] =
                        (ushort_t)(pk & 0xFFFFu);
                    v2B[gi * 4096 + swzu((ktd * 64 + ((se + 1) | (qd << 4))) * 8 + jj)] =
                        (ushort_t)(pk >> 16);
                }
            }
        }
    }
    __syncthreads();  // (2) v2B visible; all v1 reads done -> A2 region writable

    // ---- chunks: per iteration, each group's chunk c handled in parallel ----
#pragma unroll 1
    for (int c = 0; c < 2; ++c) {
        // build A2[g][m = sl*6+i][h] = m2[g][sg][h] ? w3[i][h] : 0 (waves 0-2 g0, 4-6 g1)
        // Packed C ext-vector bit-trick (bit-identical to the ternary select):
        //   relu-bf16 v has sign bit 0 -> (v+0x7fff) has bit15 set iff v!=0;
        //   mask = arith >>15 (0 / 0xFFFF per element); o = w & mask.
        if (w4 < 3) {
            const int mt = w4;
            const int m = mt * 16 + l15;
            const int sl = m / 6, i = m - sl * 6;
            const int sg = c * 8 + sl;
#pragma unroll 1
            for (int kt = 0; kt < 8; ++kt) {
                u16x8 vv = *(const u16x8*)&v2B[wg * 4096 + swzo(kt * 64 + (sg | (quad << 4))) * 8];
                bf16x8 wv = *(const bf16x8*)&g_w3b[i * 256 + kt * 32 + quad * 8];
                bf16x8 t = (bf16x8)(vv + (unsigned short)0x7fffu);  // v_pk_add_u16 (wraps)
                bf16x8 msk = t >> 15;                               // arith shift: 0 / 0xFFFF
                bf16x8 o = wv & msk;
                *(bf16x8*)&A2[wg * 12288 + swzo((mt * 8 + kt) * 64 + lane) * 8] = o;
            }
        }
        __syncthreads();  // (3) A2 visible

        // ydot tiles: wave 3 -> group 0, wave 7 -> group 1 (short; cy dies before cc loops)
        if (w4 == 3) {
            f32x4 cy[3];
#pragma unroll
            for (int mt = 0; mt < 3; ++mt) cy[mt] = (f32x4){0, 0, 0, 0};
#pragma unroll 1
            for (int kt = 0; kt < 8; ++kt) {
                bf16x8 bv = *(const bf16x8*)&v2B[wg * 4096 + swzo(kt * 64 + lane) * 8];
                __builtin_amdgcn_s_setprio(1);
#pragma unroll
                for (int mt = 0; mt < 3; ++mt) {
                    bf16x8 a = *(const bf16x8*)&A2[wg * 12288 + swzo((mt * 8 + kt) * 64 + lane) * 8];
                    cy[mt] = __builtin_amdgcn_mfma_f32_16x16x32_bf16(a, bv, cy[mt], 0, 0, 0);
                }
                __builtin_amdgcn_s_setprio(0);
            }
#pragma unroll
            for (int mt = 0; mt < 3; ++mt) {
#pragma unroll
                for (int r = 0; r < 4; ++r) {
                    const int m = mt * 16 + quad * 4 + r;
                    const int sl = m / 6, i = m - sl * 6;
                    if (l15 == c * 8 + sl) ydsh[wg * 48 + m] = cy[mt][r] + b3[i];
                }
            }
        }

        // phase C split by GROUP: pass gi computes B(gi) = A2[gi] @ w2 (M=48 N=256 K=256),
        // then (after the A2[gi]-read barrier) masks to Bm(gi) in place.
        // Live acc = 24 regs. Pass 2 re-reads the same b-frags (L2-hot).
#pragma unroll 1
        for (int gi = 0; gi < 2; ++gi) {
            f32x4 cc[3][2];  // [mt][n]
#pragma unroll
            for (int mt = 0; mt < 3; ++mt)
#pragma unroll
                for (int n = 0; n < 2; ++n) cc[mt][n] = (f32x4){0, 0, 0, 0};
#pragma unroll 1
            for (int kt = 0; kt < 8; ++kt) {
                bf16x8 a[3];
#pragma unroll
                for (int mt = 0; mt < 3; ++mt)
                    a[mt] = *(const bf16x8*)&A2[gi * 12288 + swzo((mt * 8 + kt) * 64 + lane) * 8];
#pragma unroll
                for (int n = 0; n < 2; ++n) {
                    bf16x8 b = *(const bf16x8*)&g_w2B[(((wave * 2 + n) * 8 + kt) * 64 + lane) * 8];
                    __builtin_amdgcn_s_setprio(1);
#pragma unroll
                    for (int mt = 0; mt < 3; ++mt)
                        cc[mt][n] = __builtin_amdgcn_mfma_f32_16x16x32_bf16(a[mt], b, cc[mt][n], 0, 0, 0);
                    __builtin_amdgcn_s_setprio(0);
                }
            }
            __syncthreads();  // (4.gi) all A2[gi] reads complete before Bm(gi) overwrites

            // Bm(gi) = (B .* m1) -> bf16 back into A2[gi]. Mask via m1sh (cross-wave).
            // Packed pair conversion + 32-bit AND mask (bit-identical select).
#pragma unroll
            for (int n = 0; n < 2; ++n) {
                const int j = (wave * 2 + n) * 16 + l15;  // C layout: col = lane&15
                const unsigned int mcol = m1sh[gi * 256 + j];
                const int ktd = j >> 5, qd = (j >> 3) & 3, jjd = j & 7;
#pragma unroll
                for (int mt = 0; mt < 3; ++mt) {
#pragma unroll
                    for (int rp = 0; rp < 2; ++rp) {
                        const int m0 = mt * 16 + quad * 4 + 2 * rp;  // rows m0, m0+1
                        const int sgA = c * 8 + m0 / 6;
                        const int sgB = c * 8 + (m0 + 1) / 6;
                        const unsigned int pk = f2bf_pk(cc[mt][n][2 * rp], cc[mt][n][2 * rp + 1]);
                        const unsigned int mk =
                            (((mcol >> sgA) & 1u) ? 0x0000FFFFu : 0u) |
                            (((mcol >> sgB) & 1u) ? 0xFFFF0000u : 0u);
                        const unsigned int val = pk & mk;
                        A2[gi * 12288 + swzu(((mt * 8 + ktd) * 64 + ((m0 & 15) | (qd << 4))) * 8 + jjd)] =
                            (ushort_t)(val & 0xFFFFu);
                        A2[gi * 12288 + swzu(((mt * 8 + ktd) * 64 + (((m0 + 1) & 15) | (qd << 4))) * 8 + jjd)] =
                            (ushort_t)(val >> 16);
                    }
                }
            }
        }
        __syncthreads();  // (5) Bm both groups visible

        // phase D: J = Bm @ w1e, per group M=48 N=16 K=256; waves 0-2 (g0), 4-6 (g1)
        if (w4 < 3) {
            f32x4 dc = {0, 0, 0, 0};
#pragma unroll 1
            for (int kt = 0; kt < 8; ++kt) {
                bf16x8 a = *(const bf16x8*)&A2[wg * 12288 + swzo((w4 * 8 + kt) * 64 + lane) * 8];
                bf16x8 b = *(const bf16x8*)&g_w1e[(kt * 64 + lane) * 8];
                dc = __builtin_amdgcn_mfma_f32_16x16x32_bf16(a, b, dc, 0, 0, 0);
            }
            if (l15 < 8) {
#pragma unroll
                for (int r = 0; r < 4; ++r) {
                    const int m = w4 * 16 + quad * 4 + r;
                    Jsh[(wg * 48 + m) * 8 + l15] = dc[r];
                }
            }
        }
        __syncthreads();  // (6) Jsh/ydsh visible; all Bm reads done -> next chunk may overwrite

        // coalesced output: each group's 256 threads write that group's 8 samples
        {
            const int tg = tid & 255;
            const int s0c = s0 + gz * 16 + c * 8;
            const long base6 = (long)s0c * 6;
            {
                const int u = tg;  // dy dwords 0..255
                const int s = u / 36, rem = u - s * 36, ii = rem / 6, jy = rem - ii * 6;
                out[OFF_DY + (long)s0c * 36 + u] = Jsh[(gz * 48 + s * 6 + ii) * 8 + jy];
            }
            if (tg < 32) {  // dy dwords 256..287
                const int u = 256 + tg;
                const int s = u / 36, rem = u - s * 36, ii = rem / 6, jy = rem - ii * 6;
                out[OFF_DY + (long)s0c * 36 + u] = Jsh[(gz * 48 + s * 6 + ii) * 8 + jy];
            }
            if (tg < 48) out[OFF_YDOT + base6 + tg] = ydsh[gz * 48 + tg];
            const int t2 = tg - 64;
            if (t2 >= 0 && t2 < 48) out[OFF_DE + base6 + t2] = Jsh[(gz * 48 + t2) * 8 + 6];
            const int t3 = tg - 128;
            if (t3 >= 0 && t3 < 48) out[OFF_DT + base6 + t3] = Jsh[(gz * 48 + t3) * 8 + 7];
        }
    }
}

extern "C" void kernel_launch(void* const* d_in, const int* in_sizes, int n_in,
                              void* d_out, int out_size, void* d_ws, size_t ws_size,
                              hipStream_t stream) {
    // setup_inputs order: t(0,unused), y(1), erate(2), T(3), w1(4), w2(5), w3(6), b1(7), b2(8), b3(9)
    const float* y     = (const float*)d_in[1];
    const float* erate = (const float*)d_in[2];
    const float* Tin   = (const float*)d_in[3];
    const float* w1    = (const float*)d_in[4];
    const float* w2    = (const float*)d_in[5];
    const float* w3    = (const float*)d_in[6];
    const float* b1    = (const float*)d_in[7];
    const float* b2    = (const float*)d_in[8];
    const float* b3    = (const float*)d_in[9];
    float* out = (float*)d_out;

    prep_kernel<<<dim3(64), dim3(256), 0, stream>>>(w1, w2, w3);
    fused_kernel<<<dim3(NG32), dim3(512), 0, stream>>>(
        y, erate, Tin, w1, b1, b2, b3, out);
}